// Round 7
// baseline (276.380 us; speedup 1.0000x reference)
//
#include <hip/hip_runtime.h>
#include <hip/hip_bf16.h>

// HiMambaBottleneck: B=8, C=384, H=W=32, L=1024, BL=8192, dt_rank=24, N=16.
//  - bf16 mid-pipeline; rmsnorm folded into W_in + in_proj epilogue.
//  - dt_proj folded into composite Wde = dt_w . x_w[0:24] (one GEMM).
//  - scan: 2-pass segmented 16x64; bf16-packed LDS; launch_bounds(512,4)
//    (VGPR<=128 so batched b128 reads stay in registers); scan1 closed-form
//    suffix reduction (no serial chain); scan2 serial core + butterfly +
//    LDS-stash coalesced stores.

typedef __attribute__((ext_vector_type(8))) short bf16x8;
typedef __attribute__((ext_vector_type(8))) unsigned short u16x8;
typedef __attribute__((ext_vector_type(4))) float f32x4;

#define L2E 1.44269504088896340736f

static __device__ __forceinline__ unsigned short f2bf(float f) {
  unsigned int u = __builtin_bit_cast(unsigned int, f);
  u += 0x7fff + ((u >> 16) & 1);  // RNE
  return (unsigned short)(u >> 16);
}
static __device__ __forceinline__ float bf2f(unsigned short u) {
  unsigned int v = (unsigned int)u << 16;
  return __builtin_bit_cast(float, v);
}
static __device__ __forceinline__ float bfLO(unsigned int v) {  // even t
  return __builtin_bit_cast(float, v << 16);
}
static __device__ __forceinline__ float bfHI(unsigned int v) {  // odd t
  return __builtin_bit_cast(float, v & 0xffff0000u);
}

#define GLOAD_LDS16(g, l)                                             \
  __builtin_amdgcn_global_load_lds(                                   \
      (const __attribute__((address_space(1))) unsigned int*)(g),     \
      (__attribute__((address_space(3))) unsigned int*)(l), 16, 0, 0)

// ---------------- prep: weights -> bf16 (padded), A2, Wde composite -------
__global__ __launch_bounds__(256) void prep_k(
    const float* __restrict__ in_w, const float* __restrict__ x_w,
    const float* __restrict__ dt_w, const float* __restrict__ out_w,
    const float* __restrict__ A_log, const float* __restrict__ nw,
    unsigned short* __restrict__ W_in, unsigned short* __restrict__ W_x,
    unsigned short* __restrict__ W_out, unsigned short* __restrict__ Wde,
    float* __restrict__ A2) {
  int idx = blockIdx.x * 256 + threadIdx.x;
  switch (blockIdx.y) {
    case 0: if (idx < 768 * 384) W_in[idx] = f2bf(in_w[idx] * nw[idx % 384]); break;
    case 1: if (idx < 64 * 384) { int n = idx / 384, k = idx - n * 384;
              W_x[idx] = f2bf(n < 32 ? x_w[(24 + n) * 384 + k] : 0.f); } break;
    case 2: if (idx < 384 * 384) W_out[idx] = f2bf(out_w[idx]); break;
    case 3: if (idx < 384 * 16) A2[idx] = -expf(A_log[idx]) * L2E; break;
    case 4: case 5: {
      int i2 = (blockIdx.y - 4) * 294912 + idx;   // two slabs cover 384*384
      if (i2 < 384 * 384) {
        int o = i2 / 384, c = i2 - o * 384;
        float s = 0.f;
        #pragma unroll
        for (int r = 0; r < 24; ++r) s += dt_w[o * 24 + r] * x_w[r * 384 + c];
        Wde[i2] = f2bf(s);
      }
    } break;
  }
}

// ---------------- transpose-lite: x NCHW -> xb (CL bf16) + nf[bl] ---------
__global__ __launch_bounds__(256) void transpose_k(
    const float* __restrict__ x, unsigned short* __restrict__ xb,
    float* __restrict__ nf) {
  const int b = blockIdx.y;
  const int l0 = blockIdx.x * 32;
  const int tid = threadIdx.x;
  const int cr = tid >> 5, lw = tid & 31;
  const int cj = tid & 63, lr = tid >> 6;
  __shared__ float t64[64][33];
  __shared__ float part[8][33];
  float acc = 0.f;
  for (int cc = 0; cc < 6; ++cc) {
    #pragma unroll
    for (int k = 0; k < 8; ++k) {
      int cp = k * 8 + cr;
      int c = cc * 64 + cp;
      float v = x[(((size_t)(b * 384 + c)) << 10) + l0 + lw];
      t64[cp][lw] = v;
      acc = fmaf(v, v, acc);
    }
    __syncthreads();
    #pragma unroll
    for (int k2 = 0; k2 < 8; ++k2) {
      int ll = lr + 4 * k2;
      xb[((size_t)((b << 10) + l0 + ll)) * 384 + cc * 64 + cj] = f2bf(t64[cj][ll]);
    }
    __syncthreads();
  }
  part[cr][lw] = acc;
  __syncthreads();
  if (tid < 32) {
    float s = part[0][tid] + part[1][tid] + part[2][tid] + part[3][tid] +
              part[4][tid] + part[5][tid] + part[6][tid] + part[7][tid];
    nf[(b << 10) + l0 + tid] = rsqrtf(s * (1.f / 384.f) + 1e-6f);
  }
}

// ---------------- 128^2 MFMA GEMM (m97 structure), bf16 out ---------------
// EPI 0: in_proj (out = bf16(v*nf[m]));  EPI 2: delta (softplus(v+bias[n]),
// dir via blockIdx.z);  EPI 3: out_proj (SUMIN staging S0+S1, out bf16*scale).
template <int EPI, int SUMIN>
__global__ __launch_bounds__(256) void gemm128_k(
    const unsigned short* __restrict__ A0u, const unsigned short* __restrict__ A1u,
    const unsigned short* __restrict__ Bw, int K, int N,
    unsigned short* __restrict__ ob0, unsigned short* __restrict__ ob1,
    const float* __restrict__ aux) {
  const unsigned short* Au = (EPI == 2 && blockIdx.z) ? A1u : A0u;
  unsigned short* ob = (EPI == 2 && blockIdx.z) ? ob1 : ob0;
  __shared__ __attribute__((aligned(16))) unsigned short As[128 * 32];
  __shared__ __attribute__((aligned(16))) unsigned short Bs[128 * 32];
  const int n0 = blockIdx.x * 128, m0 = blockIdx.y * 128;
  const int tid = threadIdx.x;
  const int lane = tid & 63, wave = tid >> 6;
  const int wm = wave >> 1, wn = wave & 1;
  const int fr = lane & 15, ks = (lane >> 4) * 8;
  const int row = tid >> 2, colseg = (tid & 3) * 8;
  const unsigned short* pA0 = Au + (size_t)(m0 + row) * K + colseg;
  const unsigned short* pA1 = Au + (size_t)(m0 + 64 + row) * K + colseg;
  const unsigned short* pB0 = Bw + (size_t)(n0 + row) * K + colseg;
  const unsigned short* pB1 = Bw + (size_t)(n0 + 64 + row) * K + colseg;
  unsigned short* lA0 = As + wave * 512;
  unsigned short* lA1 = As + 2048 + wave * 512;
  unsigned short* lB0 = Bs + wave * 512;
  unsigned short* lB1 = Bs + 2048 + wave * 512;
  f32x4 acc[4][4] = {};
  for (int k0 = 0; k0 < K; k0 += 32) {
    __syncthreads();
    if (SUMIN) {
      #pragma unroll
      for (int p = 0; p < 2; ++p) {
        int r = p * 64 + row;
        u16x8 va = *(const u16x8*)&A0u[(size_t)(m0 + r) * K + k0 + colseg];
        u16x8 vb = *(const u16x8*)&A1u[(size_t)(m0 + r) * K + k0 + colseg];
        u16x8 s;
        #pragma unroll
        for (int j = 0; j < 8; ++j) s[j] = f2bf(bf2f(va[j]) + bf2f(vb[j]));
        *(u16x8*)&As[r * 32 + colseg] = s;
      }
    } else {
      GLOAD_LDS16(pA0, lA0);
      GLOAD_LDS16(pA1, lA1);
      pA0 += 32; pA1 += 32;
    }
    GLOAD_LDS16(pB0, lB0);
    GLOAD_LDS16(pB1, lB1);
    pB0 += 32; pB1 += 32;
    __syncthreads();
    bf16x8 af[4], bfr[4];
    #pragma unroll
    for (int mi = 0; mi < 4; ++mi)
      af[mi] = *(const bf16x8*)&As[(wm * 64 + mi * 16 + fr) * 32 + ks];
    #pragma unroll
    for (int ni = 0; ni < 4; ++ni)
      bfr[ni] = *(const bf16x8*)&Bs[(wn * 64 + ni * 16 + fr) * 32 + ks];
    #pragma unroll
    for (int mi = 0; mi < 4; ++mi)
      #pragma unroll
      for (int ni = 0; ni < 4; ++ni)
        acc[mi][ni] = __builtin_amdgcn_mfma_f32_16x16x32_bf16(af[mi], bfr[ni], acc[mi][ni], 0, 0, 0);
  }
  #pragma unroll
  for (int mi = 0; mi < 4; ++mi)
    #pragma unroll
    for (int ni = 0; ni < 4; ++ni)
      #pragma unroll
      for (int j = 0; j < 4; ++j) {
        int m = m0 + wm * 64 + mi * 16 + (lane >> 4) * 4 + j;
        int n = n0 + wn * 64 + ni * 16 + fr;
        float v = acc[mi][ni][j];
        if (EPI == 0) {
          ob0[(size_t)m * N + n] = f2bf(v * aux[m]);        // x nf[m] -> xz
        } else if (EPI == 2) {
          float t = v + aux[n];
          float sp = (t > 20.f) ? t : log1pf(expf(t));
          ob[(size_t)m * N + n] = f2bf(sp);                 // delta bf16
        } else {
          ob0[(size_t)m * N + n] = f2bf(v * aux[0]);        // G bf16
        }
      }
}

// ---------------- small GEMM 64^2: x_proj B/C only (f32 out) --------------
__global__ __launch_bounds__(256) void gemm_bc_k(
    const unsigned short* __restrict__ A0u, const unsigned short* __restrict__ A1u,
    const unsigned short* __restrict__ Bw, int K,
    float* __restrict__ of0, float* __restrict__ of1) {
  const unsigned short* A = blockIdx.z ? A1u : A0u;
  float* outf = blockIdx.z ? of1 : of0;
  __shared__ unsigned short As[64][40];
  __shared__ unsigned short Bs[64][40];
  const int m0 = blockIdx.y * 64;
  const int tid = threadIdx.x;
  const int lane = tid & 63, wave = tid >> 6;
  const int wm = wave >> 1, wn = wave & 1;
  const int lrow = tid >> 2, lseg = (tid & 3) * 8;
  const int fr = lane & 15, ks = (lane >> 4) * 8;
  f32x4 acc[2][2] = {};
  for (int k0 = 0; k0 < K; k0 += 32) {
    __syncthreads();
    *(bf16x8*)&As[lrow][lseg] = *(const bf16x8*)&A[(size_t)(m0 + lrow) * K + k0 + lseg];
    *(bf16x8*)&Bs[lrow][lseg] = *(const bf16x8*)&Bw[(size_t)lrow * K + k0 + lseg];
    __syncthreads();
    bf16x8 a0 = *(const bf16x8*)&As[wm * 32 + fr][ks];
    bf16x8 a1 = *(const bf16x8*)&As[wm * 32 + 16 + fr][ks];
    bf16x8 b0 = *(const bf16x8*)&Bs[wn * 32 + fr][ks];
    bf16x8 b1 = *(const bf16x8*)&Bs[wn * 32 + 16 + fr][ks];
    acc[0][0] = __builtin_amdgcn_mfma_f32_16x16x32_bf16(a0, b0, acc[0][0], 0, 0, 0);
    acc[0][1] = __builtin_amdgcn_mfma_f32_16x16x32_bf16(a0, b1, acc[0][1], 0, 0, 0);
    acc[1][0] = __builtin_amdgcn_mfma_f32_16x16x32_bf16(a1, b0, acc[1][0], 0, 0, 0);
    acc[1][1] = __builtin_amdgcn_mfma_f32_16x16x32_bf16(a1, b1, acc[1][1], 0, 0, 0);
  }
  #pragma unroll
  for (int mi = 0; mi < 2; ++mi)
    #pragma unroll
    for (int ni = 0; ni < 2; ++ni)
      #pragma unroll
      for (int j = 0; j < 4; ++j) {
        int m = m0 + wm * 32 + mi * 16 + (lane >> 4) * 4 + j;
        int n = wn * 32 + ni * 16 + (lane & 15);
        if (n < 32) outf[m * 32 + n] = acc[mi][ni][j];
      }
}

// ---------------- causal depthwise conv1d + silu (both directions) --------
__global__ __launch_bounds__(384) void conv_silu_k(
    const unsigned short* __restrict__ xz, const float* __restrict__ cw,
    const float* __restrict__ cb,
    unsigned short* __restrict__ ub0, unsigned short* __restrict__ ub1) {
  const int st = blockIdx.x, b = blockIdx.y, dir = blockIdx.z;
  const int c = threadIdx.x;
  const int s0 = st * 8;
  const float w0 = cw[c * 4 + 0], w1 = cw[c * 4 + 1];
  const float w2 = cw[c * 4 + 2], w3 = cw[c * 4 + 3];
  const float bb = cb[c];
  unsigned short* ub = dir ? ub1 : ub0;
  float xv[11];
  #pragma unroll
  for (int k = 0; k < 11; ++k) {
    int j = s0 - 3 + k;
    float v = 0.f;
    if (j >= 0) {
      int t = dir ? (1023 - j) : j;
      v = bf2f(xz[(size_t)((b << 10) + t) * 768 + c]);
    }
    xv[k] = v;
  }
  #pragma unroll
  for (int s = 0; s < 8; ++s) {
    float a = bb + xv[s] * w0 + xv[s + 1] * w1 + xv[s + 2] * w2 + xv[s + 3] * w3;
    float uv = a * __builtin_amdgcn_rcpf(1.f + __builtin_amdgcn_exp2f(-a * L2E));
    ub[(size_t)((b << 10) + s0 + s) * 384 + c] = f2bf(uv);
  }
}

// ---------------- scan pass 1: closed-form (P, h) per segment -------------
// P = exp2(a2*sum(d)); h = sum_t exp2(a2*suffix_excl(t)) * (d*u)[t] * B[n][t].
// suffix >= 0 so exp2 <= 1 (safe). bf16-packed LDS, pad rows to 36 u32.
__global__ __launch_bounds__(512, 4) void scan1_k(
    const unsigned short* __restrict__ de0, const unsigned short* __restrict__ de1,
    const unsigned short* __restrict__ ub0, const unsigned short* __restrict__ ub1,
    const float* __restrict__ bc0, const float* __restrict__ bc1,
    const float* __restrict__ A2, float* __restrict__ PH) {
  const int ct = blockIdx.x, b = blockIdx.y;
  const int dir = blockIdx.z >> 4, seg = blockIdx.z & 15;
  const unsigned short* del = dir ? de1 : de0;
  const unsigned short* uu  = dir ? ub1 : ub0;
  const float* bc  = dir ? bc1 : bc0;
  const int tid = threadIdx.x;
  const int lane = tid & 63, wave = tid >> 6;
  const int n = lane & 15, cg = lane >> 4;
  const int cl = wave * 4 + cg;
  const int c = ct * 32 + cl;
  const float a2 = A2[c * 16 + n];
  const size_t base = ((size_t)b << 10) + seg * 64;
  __shared__ __attribute__((aligned(16))) unsigned int sd[32 * 36];
  __shared__ __attribute__((aligned(16))) unsigned int sdu[32 * 36];
  __shared__ __attribute__((aligned(16))) unsigned int sB[16 * 36];
  {
    const int li = tid >> 5, lj = tid & 31;
    unsigned short* sd16 = (unsigned short*)sd;
    unsigned short* sdu16 = (unsigned short*)sdu;
    #pragma unroll
    for (int k = 0; k < 4; ++k) {
      size_t rowi = base + k * 16 + li;
      unsigned short rd = del[rowi * 384 + ct * 32 + lj];
      unsigned short ru = uu [rowi * 384 + ct * 32 + lj];
      sd16[lj * 72 + k * 16 + li] = rd;
      sdu16[lj * 72 + k * 16 + li] = f2bf(bf2f(rd) * bf2f(ru));
    }
    const int li2 = tid >> 4, lj2 = tid & 15;
    unsigned short* sB16 = (unsigned short*)sB;
    #pragma unroll
    for (int k = 0; k < 2; ++k) {
      size_t rowi = base + k * 32 + li2;
      sB16[lj2 * 72 + k * 32 + li2] = f2bf(bc[rowi * 32 + lj2]);
    }
  }
  __syncthreads();
  float hA = 0.f, hB = 0.f, suf = 0.f;
  for (int ch = 3; ch >= 0; --ch) {
    uint4 qa = *(const uint4*)&sd[cl * 36 + ch * 8];
    uint4 qb = *(const uint4*)&sd[cl * 36 + ch * 8 + 4];
    uint4 ra = *(const uint4*)&sdu[cl * 36 + ch * 8];
    uint4 rb = *(const uint4*)&sdu[cl * 36 + ch * 8 + 4];
    uint4 ba = *(const uint4*)&sB[n * 36 + ch * 8];
    uint4 bb = *(const uint4*)&sB[n * 36 + ch * 8 + 4];
    unsigned int pd[8] = {qa.x, qa.y, qa.z, qa.w, qb.x, qb.y, qb.z, qb.w};
    unsigned int pu[8] = {ra.x, ra.y, ra.z, ra.w, rb.x, rb.y, rb.z, rb.w};
    unsigned int pb[8] = {ba.x, ba.y, ba.z, ba.w, bb.x, bb.y, bb.z, bb.w};
    #pragma unroll
    for (int j = 7; j >= 0; --j) {
      // t = ch*16 + 2j+1 (descending: odd first)
      float e1 = __builtin_amdgcn_exp2f(a2 * suf);
      hA = fmaf(e1, bfHI(pu[j]) * bfHI(pb[j]), hA);
      suf += bfHI(pd[j]);
      // t = ch*16 + 2j
      float e0 = __builtin_amdgcn_exp2f(a2 * suf);
      hB = fmaf(e0, bfLO(pu[j]) * bfLO(pb[j]), hB);
      suf += bfLO(pd[j]);
    }
  }
  float P = __builtin_amdgcn_exp2f(a2 * suf);
  size_t o = (size_t)((dir * 8 + b) * 16 + seg) * 6144 + c * 16 + n;
  *(float2*)&PH[o * 2] = make_float2(P, hA + hB);
}

// ---------------- scan pass 2: seeded full scan + gate (combine merged) ---
__global__ __launch_bounds__(512, 4) void scan2_k(
    const unsigned short* __restrict__ de0, const unsigned short* __restrict__ de1,
    const unsigned short* __restrict__ ub0, const unsigned short* __restrict__ ub1,
    const float* __restrict__ bc0, const float* __restrict__ bc1,
    const unsigned short* __restrict__ xz, const float* __restrict__ A2,
    const float* __restrict__ Dp, const float* __restrict__ PH,
    unsigned short* __restrict__ Sb0, unsigned short* __restrict__ Sb1) {
  const int ct = blockIdx.x, b = blockIdx.y;
  const int dir = blockIdx.z >> 4, seg = blockIdx.z & 15;
  const unsigned short* del = dir ? de1 : de0;
  const unsigned short* uu  = dir ? ub1 : ub0;
  const float* bc  = dir ? bc1 : bc0;
  unsigned short* S = dir ? Sb1 : Sb0;
  const int tid = threadIdx.x;
  const int lane = tid & 63, wave = tid >> 6;
  const int n = lane & 15, cg = lane >> 4;
  const int cl = wave * 4 + cg;
  const int c = ct * 32 + cl;
  const float a2 = A2[c * 16 + n];
  const float dpc = Dp[c];
  const size_t bb_ = (size_t)b << 10;
  const int segoff = seg * 64;
  __shared__ __attribute__((aligned(16))) unsigned int sd[32 * 36];
  __shared__ __attribute__((aligned(16))) unsigned int su[32 * 36];
  __shared__ __attribute__((aligned(16))) unsigned int sz[32 * 36];
  __shared__ __attribute__((aligned(16))) unsigned int sb[16 * 36];
  __shared__ __attribute__((aligned(16))) unsigned int sc[16 * 36];
  __shared__ __attribute__((aligned(16))) unsigned short sy[64 * 36];
  // prefix combine seed (independent loads, L2-resident)
  float h = 0.f;
  {
    size_t rb2 = (((size_t)(dir * 8 + b) * 16) * 6144 + c * 16 + n) * 2;
    #pragma unroll
    for (int s = 0; s < 15; ++s) {
      float2 ph = *(const float2*)&PH[rb2 + (size_t)s * 12288];
      h = (s < seg) ? fmaf(ph.x, h, ph.y) : h;
    }
  }
  {
    const int li = tid >> 5, lj = tid & 31;
    unsigned short* sd16 = (unsigned short*)sd;
    unsigned short* su16 = (unsigned short*)su;
    unsigned short* sz16 = (unsigned short*)sz;
    #pragma unroll
    for (int k = 0; k < 4; ++k) {
      size_t rowi = bb_ + segoff + k * 16 + li;
      sd16[lj * 72 + k * 16 + li] = del[rowi * 384 + ct * 32 + lj];
      su16[lj * 72 + k * 16 + li] = uu [rowi * 384 + ct * 32 + lj];
      int tz = dir ? (1023 - (segoff + k * 16 + li)) : (segoff + k * 16 + li);
      sz16[lj * 72 + k * 16 + li] = xz[(bb_ + tz) * 768 + 384 + ct * 32 + lj];
    }
    const int li2 = tid >> 4, lj2 = tid & 15;
    unsigned short* sb16 = (unsigned short*)sb;
    unsigned short* sc16 = (unsigned short*)sc;
    #pragma unroll
    for (int k = 0; k < 2; ++k) {
      size_t rowi = bb_ + segoff + k * 32 + li2;
      sb16[lj2 * 72 + k * 32 + li2] = f2bf(bc[rowi * 32 + lj2]);
      sc16[lj2 * 72 + k * 32 + li2] = f2bf(bc[rowi * 32 + 16 + lj2]);
    }
  }
  __syncthreads();
  for (int ch = 0; ch < 4; ++ch) {
    uint4 qa = *(const uint4*)&sd[cl * 36 + ch * 8];
    uint4 qb = *(const uint4*)&sd[cl * 36 + ch * 8 + 4];
    uint4 ra = *(const uint4*)&su[cl * 36 + ch * 8];
    uint4 rb = *(const uint4*)&su[cl * 36 + ch * 8 + 4];
    uint4 ba = *(const uint4*)&sb[n * 36 + ch * 8];
    uint4 bb2 = *(const uint4*)&sb[n * 36 + ch * 8 + 4];
    uint4 ca = *(const uint4*)&sc[n * 36 + ch * 8];
    uint4 cb = *(const uint4*)&sc[n * 36 + ch * 8 + 4];
    unsigned int pd[8] = {qa.x, qa.y, qa.z, qa.w, qb.x, qb.y, qb.z, qb.w};
    unsigned int pu[8] = {ra.x, ra.y, ra.z, ra.w, rb.x, rb.y, rb.z, rb.w};
    unsigned int pb[8] = {ba.x, ba.y, ba.z, ba.w, bb2.x, bb2.y, bb2.z, bb2.w};
    unsigned int pc[8] = {ca.x, ca.y, ca.z, ca.w, cb.x, cb.y, cb.z, cb.w};
    float p[16];
    #pragma unroll
    for (int j = 0; j < 8; ++j) {
      float dL = bfLO(pd[j]);
      float dA = __builtin_amdgcn_exp2f(dL * a2);
      h = fmaf(dA, h, dL * bfLO(pu[j]) * bfLO(pb[j]));
      p[2 * j] = h * bfLO(pc[j]);
      float dH = bfHI(pd[j]);
      dA = __builtin_amdgcn_exp2f(dH * a2);
      h = fmaf(dA, h, dH * bfHI(pu[j]) * bfHI(pb[j]));
      p[2 * j + 1] = h * bfHI(pc[j]);
    }
    // distributed butterfly: y[t] = sum_n p_n[t]; lane n ends with t=n.
    float q8[8];
    #pragma unroll
    for (int j = 0; j < 8; ++j) {
      float send = (n & 8) ? p[j] : p[j + 8];
      float recv = __shfl_xor(send, 8);
      float keep = (n & 8) ? p[j + 8] : p[j];
      q8[j] = keep + recv;
    }
    float q4[4];
    #pragma unroll
    for (int j = 0; j < 4; ++j) {
      float send = (n & 4) ? q8[j] : q8[j + 4];
      float recv = __shfl_xor(send, 4);
      float keep = (n & 4) ? q8[j + 4] : q8[j];
      q4[j] = keep + recv;
    }
    float q2[2];
    #pragma unroll
    for (int j = 0; j < 2; ++j) {
      float send = (n & 2) ? q4[j] : q4[j + 2];
      float recv = __shfl_xor(send, 2);
      float keep = (n & 2) ? q4[j + 2] : q4[j];
      q2[j] = keep + recv;
    }
    float send = (n & 1) ? q2[0] : q2[1];
    float recv = __shfl_xor(send, 1);
    float keep = (n & 1) ? q2[1] : q2[0];
    float ysum = keep + recv;
    // gate: lane n owns timestep segoff + ch*16 + n of channel c
    float uvn = bf2f(((const unsigned short*)su)[cl * 72 + ch * 16 + n]);
    float zz  = bf2f(((const unsigned short*)sz)[cl * 72 + ch * 16 + n]);
    float sig = __builtin_amdgcn_rcpf(1.f + __builtin_amdgcn_exp2f(-zz * L2E));
    float y = (ysum + uvn * dpc) * (zz * sig);
    sy[(ch * 16 + n) * 36 + cl] = f2bf(y);
  }
  __syncthreads();
  {
    const int t = tid >> 3, cq = (tid & 7) * 4;
    int tg = segoff + t;
    int trow = dir ? (1023 - tg) : tg;
    *(ushort4*)&S[(bb_ + trow) * 384 + ct * 32 + cq] =
        *(const ushort4*)&sy[t * 36 + cq];
  }
}

// ---------------- final: dwconv3x3 gate + transpose + residual ------------
__global__ __launch_bounds__(256) void final_k(
    const unsigned short* __restrict__ Gb, const unsigned short* __restrict__ xb,
    const float* __restrict__ nf, const float* __restrict__ nw,
    const float* __restrict__ x, const float* __restrict__ dww,
    const float* __restrict__ dwb, const float* __restrict__ rs,
    float* __restrict__ out) {
  __shared__ float tile[64][33];
  __shared__ float wq[9][64];
  __shared__ float bbs[64], nws[64];
  const int l0 = blockIdx.x * 32, c0 = blockIdx.y * 64, b = blockIdx.z;
  const int tid = threadIdx.x;
  for (int i = tid; i < 576; i += 256) {
    int c = i / 9, q = i - c * 9;
    wq[q][c] = dww[(size_t)(c0 + c) * 9 + q] * nw[c0 + c];
  }
  if (tid < 64) { bbs[tid] = dwb[c0 + tid]; nws[tid] = nw[c0 + tid]; }
  __syncthreads();
  {
    const int oct = tid & 7, li = tid >> 3;
    const int l = l0 + li;
    const int hh = l >> 5, ww = l & 31;
    float acc[8];
    {
      f32x4 ba = *(const f32x4*)&bbs[oct * 8];
      f32x4 bb2 = *(const f32x4*)&bbs[oct * 8 + 4];
      #pragma unroll
      for (int j = 0; j < 4; ++j) { acc[j] = ba[j]; acc[j + 4] = bb2[j]; }
    }
    #pragma unroll
    for (int di = -1; di <= 1; ++di) {
      int h2 = hh + di;
      if (h2 < 0 || h2 > 31) continue;
      #pragma unroll
      for (int dj = -1; dj <= 1; ++dj) {
        int w2 = ww + dj;
        if (w2 < 0 || w2 > 31) continue;
        int lp = h2 * 32 + w2;
        float nfl = nf[(b << 10) + lp];
        u16x8 v = *(const u16x8*)&xb[(size_t)((b << 10) + lp) * 384 + c0 + oct * 8];
        int q = (di + 1) * 3 + (dj + 1);
        f32x4 wa = *(const f32x4*)&wq[q][oct * 8];
        f32x4 wb = *(const f32x4*)&wq[q][oct * 8 + 4];
        #pragma unroll
        for (int j = 0; j < 4; ++j) {
          acc[j]     = fmaf(bf2f(v[j]) * nfl, wa[j], acc[j]);
          acc[j + 4] = fmaf(bf2f(v[j + 4]) * nfl, wb[j], acc[j + 4]);
        }
      }
    }
    size_t ri = (size_t)((b << 10) + l) * 384 + c0 + oct * 8;
    float nfl0 = nf[(b << 10) + l];
    u16x8 xc = *(const u16x8*)&xb[ri];
    u16x8 gv = *(const u16x8*)&Gb[ri];
    #pragma unroll
    for (int j = 0; j < 8; ++j) {
      float xv = bf2f(xc[j]) * nfl0 * nws[oct * 8 + j];
      float sig = __builtin_amdgcn_rcpf(1.f + __builtin_amdgcn_exp2f(-acc[j] * L2E));
      tile[oct * 8 + j][li] = bf2f(gv[j]) + xv * sig;
    }
  }
  __syncthreads();
  {
    const int lw = tid & 31, cr = tid >> 5;
    const float rsv = rs[0];
    for (int p = 0; p < 8; ++p) {
      int c = c0 + p * 8 + cr;
      size_t o = ((size_t)(b * 384 + c) << 10) + l0 + lw;
      out[o] = x[o] + rsv * tile[p * 8 + cr][lw];
    }
  }
}

// ---------------- host ----------------------------------------------------
extern "C" void kernel_launch(void* const* d_in, const int* in_sizes, int n_in,
                              void* d_out, int out_size, void* d_ws, size_t ws_size,
                              hipStream_t stream) {
  const float* x         = (const float*)d_in[0];
  const float* norm_w    = (const float*)d_in[1];
  const float* in_proj_w = (const float*)d_in[2];
  const float* conv1d_w  = (const float*)d_in[3];
  const float* conv1d_b  = (const float*)d_in[4];
  const float* x_proj_w  = (const float*)d_in[5];
  const float* dt_proj_w = (const float*)d_in[6];
  const float* dt_proj_b = (const float*)d_in[7];
  const float* A_log     = (const float*)d_in[8];
  const float* D_param   = (const float*)d_in[9];
  const float* out_proj_w= (const float*)d_in[10];
  const float* scale_mod = (const float*)d_in[11];
  const float* dw_w      = (const float*)d_in[12];
  const float* dw_b      = (const float*)d_in[13];
  const float* res_scale = (const float*)d_in[14];
  float* out = (float*)d_out;

  char* base = (char*)d_ws;
  size_t off = 0;
  auto alloc = [&](size_t bytes) {
    off = (off + 255) & ~(size_t)255;
    void* p = base + off;
    off += bytes;
    return p;
  };
  const size_t B_BLC = (size_t)8192 * 384 * 2;

  unsigned short* xb   = (unsigned short*)alloc(B_BLC);
  float*          nf   = (float*)alloc((size_t)8192 * 4);
  unsigned short* xz   = (unsigned short*)alloc((size_t)8192 * 768 * 2);
  unsigned short* u_b0 = (unsigned short*)alloc(B_BLC);
  unsigned short* u_b1 = (unsigned short*)alloc(B_BLC);
  float*          bc0  = (float*)alloc((size_t)8192 * 32 * 4);
  float*          bc1  = (float*)alloc((size_t)8192 * 32 * 4);
  unsigned short* de0  = (unsigned short*)alloc(B_BLC);
  unsigned short* de1  = (unsigned short*)alloc(B_BLC);
  unsigned short* Sb0  = (unsigned short*)alloc(B_BLC);
  unsigned short* Sb1  = (unsigned short*)alloc(B_BLC);
  float*          PH   = (float*)alloc((size_t)1572864 * 2 * 4);
  unsigned short* W_in = (unsigned short*)alloc((size_t)768 * 384 * 2);
  unsigned short* W_x  = (unsigned short*)alloc((size_t)64 * 384 * 2);
  unsigned short* W_out= (unsigned short*)alloc((size_t)384 * 384 * 2);
  unsigned short* Wde  = (unsigned short*)alloc((size_t)384 * 384 * 2);
  float*          A2   = (float*)alloc((size_t)384 * 16 * 4);
  unsigned short* Gb   = (unsigned short*)alloc(B_BLC);

  prep_k<<<dim3(1152, 6), 256, 0, stream>>>(in_proj_w, x_proj_w, dt_proj_w,
                                            out_proj_w, A_log, norm_w,
                                            W_in, W_x, W_out, Wde, A2);
  transpose_k<<<dim3(32, 8), 256, 0, stream>>>(x, xb, nf);
  gemm128_k<0, 0><<<dim3(6, 64), 256, 0, stream>>>(xb, xb, W_in, 384, 768,
                                                   xz, xz, nf);
  conv_silu_k<<<dim3(128, 8, 2), 384, 0, stream>>>(xz, conv1d_w, conv1d_b,
                                                   u_b0, u_b1);
  gemm_bc_k<<<dim3(1, 128, 2), 256, 0, stream>>>(u_b0, u_b1, W_x, 384,
                                                 bc0, bc1);
  gemm128_k<2, 0><<<dim3(3, 64, 2), 256, 0, stream>>>(u_b0, u_b1, Wde, 384, 384,
                                                      de0, de1, dt_proj_b);
  scan1_k<<<dim3(12, 8, 32), 512, 0, stream>>>(de0, de1, u_b0, u_b1, bc0, bc1,
                                               A2, PH);
  scan2_k<<<dim3(12, 8, 32), 512, 0, stream>>>(de0, de1, u_b0, u_b1, bc0, bc1,
                                               xz, A2, D_param, PH, Sb0, Sb1);
  gemm128_k<3, 1><<<dim3(3, 64), 256, 0, stream>>>(Sb0, Sb1, W_out, 384, 384,
                                                   Gb, Gb, scale_mod);
  final_k<<<dim3(32, 6, 8), 256, 0, stream>>>(Gb, xb, nf, norm_w, x, dw_w, dw_b,
                                              res_scale, out);
}

// Round 8
// 263.418 us; speedup vs baseline: 1.0492x; 1.0492x over previous
//
#include <hip/hip_runtime.h>
#include <hip/hip_bf16.h>

// HiMambaBottleneck: B=8, C=384, H=W=32, L=1024, BL=8192, dt_rank=24, N=16.
//  - bf16 mid-pipeline; rmsnorm folded into W_in + in_proj epilogue.
//  - delta GEMM fused with x_proj B/C via combined weight Wcomb[512][384].
//  - scan: 2-pass segmented 16x64, f32 LDS (R6 structure), prefetch-all +
//    single barrier; scan2 adds LDS y-stash -> coalesced ushort4 stores.

typedef __attribute__((ext_vector_type(8))) short bf16x8;
typedef __attribute__((ext_vector_type(8))) unsigned short u16x8;
typedef __attribute__((ext_vector_type(4))) float f32x4;

#define L2E 1.44269504088896340736f

static __device__ __forceinline__ unsigned short f2bf(float f) {
  unsigned int u = __builtin_bit_cast(unsigned int, f);
  u += 0x7fff + ((u >> 16) & 1);  // RNE
  return (unsigned short)(u >> 16);
}
static __device__ __forceinline__ float bf2f(unsigned short u) {
  unsigned int v = (unsigned int)u << 16;
  return __builtin_bit_cast(float, v);
}

#define GLOAD_LDS16(g, l)                                             \
  __builtin_amdgcn_global_load_lds(                                   \
      (const __attribute__((address_space(1))) unsigned int*)(g),     \
      (__attribute__((address_space(3))) unsigned int*)(l), 16, 0, 0)

// ---------------- prep: weights -> bf16 (padded), A2, Wcomb ---------------
__global__ __launch_bounds__(256) void prep_k(
    const float* __restrict__ in_w, const float* __restrict__ x_w,
    const float* __restrict__ dt_w, const float* __restrict__ out_w,
    const float* __restrict__ A_log, const float* __restrict__ nw,
    unsigned short* __restrict__ W_in, unsigned short* __restrict__ W_out,
    unsigned short* __restrict__ Wcomb, float* __restrict__ A2) {
  int idx = blockIdx.x * 256 + threadIdx.x;
  switch (blockIdx.y) {
    case 0: if (idx < 768 * 384) W_in[idx] = f2bf(in_w[idx] * nw[idx % 384]); break;
    case 1: if (idx < 384 * 384) W_out[idx] = f2bf(out_w[idx]); break;
    case 2: if (idx < 384 * 16) A2[idx] = -expf(A_log[idx]) * L2E; break;
    case 3: if (idx < 384 * 384) {            // Wcomb rows 0..383: dt_w . x_w
        int o = idx / 384, c = idx - o * 384;
        float s = 0.f;
        #pragma unroll
        for (int r = 0; r < 24; ++r) s += dt_w[o * 24 + r] * x_w[r * 384 + c];
        Wcomb[idx] = f2bf(s);
      } break;
    case 4: if (idx < 128 * 384) {            // Wcomb rows 384..511: B/C + pad
        int n = idx / 384, k = idx - n * 384;
        Wcomb[147456 + idx] = f2bf(n < 32 ? x_w[(24 + n) * 384 + k] : 0.f);
      } break;
  }
}

// ---------------- transpose-lite: x NCHW -> xb (CL bf16) + nf[bl] ---------
__global__ __launch_bounds__(256) void transpose_k(
    const float* __restrict__ x, unsigned short* __restrict__ xb,
    float* __restrict__ nf) {
  const int b = blockIdx.y;
  const int l0 = blockIdx.x * 32;
  const int tid = threadIdx.x;
  const int cr = tid >> 5, lw = tid & 31;
  const int cj = tid & 63, lr = tid >> 6;
  __shared__ float t64[64][33];
  __shared__ float part[8][33];
  float acc = 0.f;
  for (int cc = 0; cc < 6; ++cc) {
    #pragma unroll
    for (int k = 0; k < 8; ++k) {
      int cp = k * 8 + cr;
      int c = cc * 64 + cp;
      float v = x[(((size_t)(b * 384 + c)) << 10) + l0 + lw];
      t64[cp][lw] = v;
      acc = fmaf(v, v, acc);
    }
    __syncthreads();
    #pragma unroll
    for (int k2 = 0; k2 < 8; ++k2) {
      int ll = lr + 4 * k2;
      xb[((size_t)((b << 10) + l0 + ll)) * 384 + cc * 64 + cj] = f2bf(t64[cj][ll]);
    }
    __syncthreads();
  }
  part[cr][lw] = acc;
  __syncthreads();
  if (tid < 32) {
    float s = part[0][tid] + part[1][tid] + part[2][tid] + part[3][tid] +
              part[4][tid] + part[5][tid] + part[6][tid] + part[7][tid];
    nf[(b << 10) + l0 + tid] = rsqrtf(s * (1.f / 384.f) + 1e-6f);
  }
}

// ---------------- 128^2 MFMA GEMM (m97 structure) -------------------------
// EPI 0: in_proj (bf16 out x nf[m]); EPI 2: delta+bc combined (N=512:
// n<384 softplus->de bf16, 384<=n<416 -> bc f32); EPI 3: out_proj
// (SUMIN staging S0+S1, out bf16 x scale).
template <int EPI, int SUMIN>
__global__ __launch_bounds__(256) void gemm128_k(
    const unsigned short* __restrict__ A0u, const unsigned short* __restrict__ A1u,
    const unsigned short* __restrict__ Bw, int K, int N,
    unsigned short* __restrict__ ob0, unsigned short* __restrict__ ob1,
    float* __restrict__ of0, float* __restrict__ of1,
    const float* __restrict__ aux) {
  const unsigned short* Au = (EPI == 2 && blockIdx.z) ? A1u : A0u;
  unsigned short* ob = (EPI == 2 && blockIdx.z) ? ob1 : ob0;
  float* of = (EPI == 2 && blockIdx.z) ? of1 : of0;
  __shared__ __attribute__((aligned(16))) unsigned short As[128 * 32];
  __shared__ __attribute__((aligned(16))) unsigned short Bs[128 * 32];
  const int n0 = blockIdx.x * 128, m0 = blockIdx.y * 128;
  const int tid = threadIdx.x;
  const int lane = tid & 63, wave = tid >> 6;
  const int wm = wave >> 1, wn = wave & 1;
  const int fr = lane & 15, ks = (lane >> 4) * 8;
  const int row = tid >> 2, colseg = (tid & 3) * 8;
  const unsigned short* pA0 = Au + (size_t)(m0 + row) * K + colseg;
  const unsigned short* pA1 = Au + (size_t)(m0 + 64 + row) * K + colseg;
  const unsigned short* pB0 = Bw + (size_t)(n0 + row) * K + colseg;
  const unsigned short* pB1 = Bw + (size_t)(n0 + 64 + row) * K + colseg;
  unsigned short* lA0 = As + wave * 512;
  unsigned short* lA1 = As + 2048 + wave * 512;
  unsigned short* lB0 = Bs + wave * 512;
  unsigned short* lB1 = Bs + 2048 + wave * 512;
  f32x4 acc[4][4] = {};
  for (int k0 = 0; k0 < K; k0 += 32) {
    __syncthreads();
    if (SUMIN) {
      #pragma unroll
      for (int p = 0; p < 2; ++p) {
        int r = p * 64 + row;
        u16x8 va = *(const u16x8*)&A0u[(size_t)(m0 + r) * K + k0 + colseg];
        u16x8 vb = *(const u16x8*)&A1u[(size_t)(m0 + r) * K + k0 + colseg];
        u16x8 s;
        #pragma unroll
        for (int j = 0; j < 8; ++j) s[j] = f2bf(bf2f(va[j]) + bf2f(vb[j]));
        *(u16x8*)&As[r * 32 + colseg] = s;
      }
    } else {
      GLOAD_LDS16(pA0, lA0);
      GLOAD_LDS16(pA1, lA1);
      pA0 += 32; pA1 += 32;
    }
    GLOAD_LDS16(pB0, lB0);
    GLOAD_LDS16(pB1, lB1);
    pB0 += 32; pB1 += 32;
    __syncthreads();
    bf16x8 af[4], bfr[4];
    #pragma unroll
    for (int mi = 0; mi < 4; ++mi)
      af[mi] = *(const bf16x8*)&As[(wm * 64 + mi * 16 + fr) * 32 + ks];
    #pragma unroll
    for (int ni = 0; ni < 4; ++ni)
      bfr[ni] = *(const bf16x8*)&Bs[(wn * 64 + ni * 16 + fr) * 32 + ks];
    #pragma unroll
    for (int mi = 0; mi < 4; ++mi)
      #pragma unroll
      for (int ni = 0; ni < 4; ++ni)
        acc[mi][ni] = __builtin_amdgcn_mfma_f32_16x16x32_bf16(af[mi], bfr[ni], acc[mi][ni], 0, 0, 0);
  }
  #pragma unroll
  for (int mi = 0; mi < 4; ++mi)
    #pragma unroll
    for (int ni = 0; ni < 4; ++ni)
      #pragma unroll
      for (int j = 0; j < 4; ++j) {
        int m = m0 + wm * 64 + mi * 16 + (lane >> 4) * 4 + j;
        int n = n0 + wn * 64 + ni * 16 + fr;
        float v = acc[mi][ni][j];
        if (EPI == 0) {
          ob0[(size_t)m * N + n] = f2bf(v * aux[m]);        // x nf[m] -> xz
        } else if (EPI == 2) {
          if (n < 384) {
            float t = v + aux[n];
            float sp = (t > 20.f) ? t : log1pf(expf(t));
            ob[(size_t)m * 384 + n] = f2bf(sp);             // delta bf16
          } else if (n < 416) {
            of[(size_t)m * 32 + (n - 384)] = v;             // B/C f32
          }
        } else {
          ob0[(size_t)m * N + n] = f2bf(v * aux[0]);        // G bf16
        }
      }
}

// ---------------- causal depthwise conv1d + silu (both directions) --------
__global__ __launch_bounds__(384) void conv_silu_k(
    const unsigned short* __restrict__ xz, const float* __restrict__ cw,
    const float* __restrict__ cb,
    unsigned short* __restrict__ ub0, unsigned short* __restrict__ ub1) {
  const int st = blockIdx.x, b = blockIdx.y, dir = blockIdx.z;
  const int c = threadIdx.x;
  const int s0 = st * 8;
  const float w0 = cw[c * 4 + 0], w1 = cw[c * 4 + 1];
  const float w2 = cw[c * 4 + 2], w3 = cw[c * 4 + 3];
  const float bb = cb[c];
  unsigned short* ub = dir ? ub1 : ub0;
  float xv[11];
  #pragma unroll
  for (int k = 0; k < 11; ++k) {
    int j = s0 - 3 + k;
    float v = 0.f;
    if (j >= 0) {
      int t = dir ? (1023 - j) : j;
      v = bf2f(xz[(size_t)((b << 10) + t) * 768 + c]);
    }
    xv[k] = v;
  }
  #pragma unroll
  for (int s = 0; s < 8; ++s) {
    float a = bb + xv[s] * w0 + xv[s + 1] * w1 + xv[s + 2] * w2 + xv[s + 3] * w3;
    float uv = a * __builtin_amdgcn_rcpf(1.f + __builtin_amdgcn_exp2f(-a * L2E));
    ub[(size_t)((b << 10) + s0 + s) * 384 + c] = f2bf(uv);
  }
}

// ---------------- scan pass 1: per-segment (P, h) -> PH interleaved -------
// grid (12 ct, 8 b, 32 = dir*16+seg); 512 thr; prefetch-all, 1 barrier.
__global__ __launch_bounds__(512) void scan1_k(
    const unsigned short* __restrict__ de0, const unsigned short* __restrict__ de1,
    const unsigned short* __restrict__ ub0, const unsigned short* __restrict__ ub1,
    const float* __restrict__ bc0, const float* __restrict__ bc1,
    const float* __restrict__ A2, float* __restrict__ PH) {
  const int ct = blockIdx.x, b = blockIdx.y;
  const int dir = blockIdx.z >> 4, seg = blockIdx.z & 15;
  const unsigned short* del = dir ? de1 : de0;
  const unsigned short* uu  = dir ? ub1 : ub0;
  const float* bc  = dir ? bc1 : bc0;
  const int tid = threadIdx.x;
  const int lane = tid & 63, wave = tid >> 6;
  const int n = lane & 15, cg = lane >> 4;
  const int cl = wave * 4 + cg;
  const int c = ct * 32 + cl;
  const float a2 = A2[c * 16 + n];
  const size_t base = ((size_t)b << 10) + seg * 64;
  __shared__ __attribute__((aligned(16))) float sd[32][68];
  __shared__ __attribute__((aligned(16))) float su[32][68];
  __shared__ __attribute__((aligned(16))) float sB[16][68];
  const int li = tid >> 5, lj = tid & 31;
  const int li3 = tid >> 4, lj3 = tid & 15;
  unsigned short rd[4], ru[4];
  float rb[2];
  #pragma unroll
  for (int k = 0; k < 4; ++k) {
    size_t rowi = base + k * 16 + li;
    rd[k] = del[rowi * 384 + ct * 32 + lj];
    ru[k] = uu [rowi * 384 + ct * 32 + lj];
  }
  #pragma unroll
  for (int k = 0; k < 2; ++k)
    rb[k] = bc[(base + k * 32 + li3) * 32 + lj3];
  #pragma unroll
  for (int k = 0; k < 4; ++k) {
    float dd = bf2f(rd[k]);
    sd[lj][k * 16 + li] = dd;
    su[lj][k * 16 + li] = dd * bf2f(ru[k]);   // premultiplied d*u
  }
  #pragma unroll
  for (int k = 0; k < 2; ++k) sB[lj3][k * 32 + li3] = rb[k];
  __syncthreads();
  float h = 0.f, P = 1.f;
  for (int ch = 0; ch < 4; ++ch) {
    f32x4 dv[4], duv[4], bmv[4];
    #pragma unroll
    for (int r = 0; r < 4; ++r) {
      dv[r]  = *(const f32x4*)&sd[cl][ch * 16 + r * 4];
      duv[r] = *(const f32x4*)&su[cl][ch * 16 + r * 4];
      bmv[r] = *(const f32x4*)&sB[n][ch * 16 + r * 4];
    }
    #pragma unroll
    for (int i = 0; i < 16; ++i) {
      float dA = __builtin_amdgcn_exp2f(dv[i >> 2][i & 3] * a2);
      h = fmaf(dA, h, duv[i >> 2][i & 3] * bmv[i >> 2][i & 3]);
      P *= dA;
    }
  }
  size_t o = (size_t)((dir * 8 + b) * 16 + seg) * 6144 + c * 16 + n;
  *(float2*)&PH[o * 2] = make_float2(P, h);
}

// ---------------- scan pass 2: seeded full scan + gate (combine merged) ---
__global__ __launch_bounds__(512) void scan2_k(
    const unsigned short* __restrict__ de0, const unsigned short* __restrict__ de1,
    const unsigned short* __restrict__ ub0, const unsigned short* __restrict__ ub1,
    const float* __restrict__ bc0, const float* __restrict__ bc1,
    const unsigned short* __restrict__ xz, const float* __restrict__ A2,
    const float* __restrict__ Dp, const float* __restrict__ PH,
    unsigned short* __restrict__ Sb0, unsigned short* __restrict__ Sb1) {
  const int ct = blockIdx.x, b = blockIdx.y;
  const int dir = blockIdx.z >> 4, seg = blockIdx.z & 15;
  const unsigned short* del = dir ? de1 : de0;
  const unsigned short* uu  = dir ? ub1 : ub0;
  const float* bc  = dir ? bc1 : bc0;
  unsigned short* S = dir ? Sb1 : Sb0;
  const int tid = threadIdx.x;
  const int lane = tid & 63, wave = tid >> 6;
  const int n = lane & 15, cg = lane >> 4;
  const int cl = wave * 4 + cg;
  const int c = ct * 32 + cl;
  const float a2 = A2[c * 16 + n];
  const float dpc = Dp[c];
  const size_t bb_ = (size_t)b << 10;
  const int segoff = seg * 64;
  __shared__ __attribute__((aligned(16))) float sd[32][68];
  __shared__ __attribute__((aligned(16))) float su[32][68];
  __shared__ __attribute__((aligned(16))) float sz[32][68];
  __shared__ __attribute__((aligned(16))) float sbc[32][68];
  __shared__ __attribute__((aligned(16))) unsigned short sy[64 * 36];
  const int li = tid >> 5, lj = tid & 31;
  unsigned short rd[4], ru[4], rz[4];
  float rb[4];
  #pragma unroll
  for (int k = 0; k < 4; ++k) {
    size_t rowi = bb_ + segoff + k * 16 + li;
    rd[k] = del[rowi * 384 + ct * 32 + lj];
    ru[k] = uu [rowi * 384 + ct * 32 + lj];
    int tz = dir ? (1023 - (segoff + k * 16 + li)) : (segoff + k * 16 + li);
    rz[k] = xz[(bb_ + tz) * 768 + 384 + ct * 32 + lj];
    rb[k] = bc[rowi * 32 + lj];
  }
  // prefix combine seed (independent loads, L2-resident)
  float h = 0.f;
  {
    size_t rb2 = (((size_t)(dir * 8 + b) * 16) * 6144 + c * 16 + n) * 2;
    #pragma unroll
    for (int s = 0; s < 15; ++s) {
      float2 ph = *(const float2*)&PH[rb2 + (size_t)s * 12288];
      h = (s < seg) ? fmaf(ph.x, h, ph.y) : h;
    }
  }
  #pragma unroll
  for (int k = 0; k < 4; ++k) {
    sd[lj][k * 16 + li] = bf2f(rd[k]);
    su[lj][k * 16 + li] = bf2f(ru[k]);
    sz[lj][k * 16 + li] = bf2f(rz[k]);
    sbc[lj][k * 16 + li] = rb[k];
  }
  __syncthreads();
  for (int ch = 0; ch < 4; ++ch) {
    f32x4 dv[4], uv4[4], bmv[4], cmv[4];
    #pragma unroll
    for (int r = 0; r < 4; ++r) {
      dv[r]  = *(const f32x4*)&sd[cl][ch * 16 + r * 4];
      uv4[r] = *(const f32x4*)&su[cl][ch * 16 + r * 4];
      bmv[r] = *(const f32x4*)&sbc[n][ch * 16 + r * 4];
      cmv[r] = *(const f32x4*)&sbc[16 + n][ch * 16 + r * 4];
    }
    float p[16];
    #pragma unroll
    for (int i = 0; i < 16; ++i) {
      float dd = dv[i >> 2][i & 3];
      float dA = __builtin_amdgcn_exp2f(dd * a2);
      h = fmaf(dA, h, dd * uv4[i >> 2][i & 3] * bmv[i >> 2][i & 3]);
      p[i] = h * cmv[i >> 2][i & 3];
    }
    // distributed butterfly: y[t] = sum_n p_n[t]; lane n ends with t=n.
    float q8[8];
    #pragma unroll
    for (int j = 0; j < 8; ++j) {
      float send = (n & 8) ? p[j] : p[j + 8];
      float recv = __shfl_xor(send, 8);
      float keep = (n & 8) ? p[j + 8] : p[j];
      q8[j] = keep + recv;
    }
    float q4[4];
    #pragma unroll
    for (int j = 0; j < 4; ++j) {
      float send = (n & 4) ? q8[j] : q8[j + 4];
      float recv = __shfl_xor(send, 4);
      float keep = (n & 4) ? q8[j + 4] : q8[j];
      q4[j] = keep + recv;
    }
    float q2[2];
    #pragma unroll
    for (int j = 0; j < 2; ++j) {
      float send = (n & 2) ? q4[j] : q4[j + 2];
      float recv = __shfl_xor(send, 2);
      float keep = (n & 2) ? q4[j + 2] : q4[j];
      q2[j] = keep + recv;
    }
    float send = (n & 1) ? q2[0] : q2[1];
    float recv = __shfl_xor(send, 1);
    float keep = (n & 1) ? q2[1] : q2[0];
    float ysum = keep + recv;
    // gate: lane n owns timestep segoff + ch*16 + n of channel c
    float uvn = su[cl][ch * 16 + n];
    float zz  = sz[cl][ch * 16 + n];
    float sig = __builtin_amdgcn_rcpf(1.f + __builtin_amdgcn_exp2f(-zz * L2E));
    float y = (ysum + uvn * dpc) * (zz * sig);
    sy[(ch * 16 + n) * 36 + cl] = f2bf(y);
  }
  __syncthreads();
  {
    const int t = tid >> 3, cq = (tid & 7) * 4;
    int tg = segoff + t;
    int trow = dir ? (1023 - tg) : tg;
    *(ushort4*)&S[(bb_ + trow) * 384 + ct * 32 + cq] =
        *(const ushort4*)&sy[t * 36 + cq];
  }
}

// ---------------- final: dwconv3x3 gate + transpose + residual ------------
__global__ __launch_bounds__(256) void final_k(
    const unsigned short* __restrict__ Gb, const unsigned short* __restrict__ xb,
    const float* __restrict__ nf, const float* __restrict__ nw,
    const float* __restrict__ x, const float* __restrict__ dww,
    const float* __restrict__ dwb, const float* __restrict__ rs,
    float* __restrict__ out) {
  __shared__ float tile[64][33];
  __shared__ float wq[9][64];
  __shared__ float bbs[64], nws[64];
  const int l0 = blockIdx.x * 32, c0 = blockIdx.y * 64, b = blockIdx.z;
  const int tid = threadIdx.x;
  for (int i = tid; i < 576; i += 256) {
    int c = i / 9, q = i - c * 9;
    wq[q][c] = dww[(size_t)(c0 + c) * 9 + q] * nw[c0 + c];
  }
  if (tid < 64) { bbs[tid] = dwb[c0 + tid]; nws[tid] = nw[c0 + tid]; }
  __syncthreads();
  {
    const int oct = tid & 7, li = tid >> 3;
    const int l = l0 + li;
    const int hh = l >> 5, ww = l & 31;
    float acc[8];
    {
      f32x4 ba = *(const f32x4*)&bbs[oct * 8];
      f32x4 bb2 = *(const f32x4*)&bbs[oct * 8 + 4];
      #pragma unroll
      for (int j = 0; j < 4; ++j) { acc[j] = ba[j]; acc[j + 4] = bb2[j]; }
    }
    #pragma unroll
    for (int di = -1; di <= 1; ++di) {
      int h2 = hh + di;
      if (h2 < 0 || h2 > 31) continue;
      #pragma unroll
      for (int dj = -1; dj <= 1; ++dj) {
        int w2 = ww + dj;
        if (w2 < 0 || w2 > 31) continue;
        int lp = h2 * 32 + w2;
        float nfl = nf[(b << 10) + lp];
        u16x8 v = *(const u16x8*)&xb[(size_t)((b << 10) + lp) * 384 + c0 + oct * 8];
        int q = (di + 1) * 3 + (dj + 1);
        f32x4 wa = *(const f32x4*)&wq[q][oct * 8];
        f32x4 wb = *(const f32x4*)&wq[q][oct * 8 + 4];
        #pragma unroll
        for (int j = 0; j < 4; ++j) {
          acc[j]     = fmaf(bf2f(v[j]) * nfl, wa[j], acc[j]);
          acc[j + 4] = fmaf(bf2f(v[j + 4]) * nfl, wb[j], acc[j + 4]);
        }
      }
    }
    size_t ri = (size_t)((b << 10) + l) * 384 + c0 + oct * 8;
    float nfl0 = nf[(b << 10) + l];
    u16x8 xc = *(const u16x8*)&xb[ri];
    u16x8 gv = *(const u16x8*)&Gb[ri];
    #pragma unroll
    for (int j = 0; j < 8; ++j) {
      float xv = bf2f(xc[j]) * nfl0 * nws[oct * 8 + j];
      float sig = __builtin_amdgcn_rcpf(1.f + __builtin_amdgcn_exp2f(-acc[j] * L2E));
      tile[oct * 8 + j][li] = bf2f(gv[j]) + xv * sig;
    }
  }
  __syncthreads();
  {
    const int lw = tid & 31, cr = tid >> 5;
    const float rsv = rs[0];
    for (int p = 0; p < 8; ++p) {
      int c = c0 + p * 8 + cr;
      size_t o = ((size_t)(b * 384 + c) << 10) + l0 + lw;
      out[o] = x[o] + rsv * tile[p * 8 + cr][lw];
    }
  }
}

// ---------------- host ----------------------------------------------------
extern "C" void kernel_launch(void* const* d_in, const int* in_sizes, int n_in,
                              void* d_out, int out_size, void* d_ws, size_t ws_size,
                              hipStream_t stream) {
  const float* x         = (const float*)d_in[0];
  const float* norm_w    = (const float*)d_in[1];
  const float* in_proj_w = (const float*)d_in[2];
  const float* conv1d_w  = (const float*)d_in[3];
  const float* conv1d_b  = (const float*)d_in[4];
  const float* x_proj_w  = (const float*)d_in[5];
  const float* dt_proj_w = (const float*)d_in[6];
  const float* dt_proj_b = (const float*)d_in[7];
  const float* A_log     = (const float*)d_in[8];
  const float* D_param   = (const float*)d_in[9];
  const float* out_proj_w= (const float*)d_in[10];
  const float* scale_mod = (const float*)d_in[11];
  const float* dw_w      = (const float*)d_in[12];
  const float* dw_b      = (const float*)d_in[13];
  const float* res_scale = (const float*)d_in[14];
  float* out = (float*)d_out;

  char* base = (char*)d_ws;
  size_t off = 0;
  auto alloc = [&](size_t bytes) {
    off = (off + 255) & ~(size_t)255;
    void* p = base + off;
    off += bytes;
    return p;
  };
  const size_t B_BLC = (size_t)8192 * 384 * 2;

  unsigned short* xb   = (unsigned short*)alloc(B_BLC);
  float*          nf   = (float*)alloc((size_t)8192 * 4);
  unsigned short* xz   = (unsigned short*)alloc((size_t)8192 * 768 * 2);
  unsigned short* u_b0 = (unsigned short*)alloc(B_BLC);
  unsigned short* u_b1 = (unsigned short*)alloc(B_BLC);
  float*          bc0  = (float*)alloc((size_t)8192 * 32 * 4);
  float*          bc1  = (float*)alloc((size_t)8192 * 32 * 4);
  unsigned short* de0  = (unsigned short*)alloc(B_BLC);
  unsigned short* de1  = (unsigned short*)alloc(B_BLC);
  unsigned short* Sb0  = (unsigned short*)alloc(B_BLC);
  unsigned short* Sb1  = (unsigned short*)alloc(B_BLC);
  float*          PH   = (float*)alloc((size_t)1572864 * 2 * 4);
  unsigned short* W_in = (unsigned short*)alloc((size_t)768 * 384 * 2);
  unsigned short* W_out= (unsigned short*)alloc((size_t)384 * 384 * 2);
  unsigned short* Wcomb= (unsigned short*)alloc((size_t)512 * 384 * 2);
  float*          A2   = (float*)alloc((size_t)384 * 16 * 4);
  unsigned short* Gb   = (unsigned short*)alloc(B_BLC);

  prep_k<<<dim3(1152, 5), 256, 0, stream>>>(in_proj_w, x_proj_w, dt_proj_w,
                                            out_proj_w, A_log, norm_w,
                                            W_in, W_out, Wcomb, A2);
  transpose_k<<<dim3(32, 8), 256, 0, stream>>>(x, xb, nf);
  gemm128_k<0, 0><<<dim3(6, 64), 256, 0, stream>>>(xb, xb, W_in, 384, 768,
                                                   xz, xz, nullptr, nullptr, nf);
  conv_silu_k<<<dim3(128, 8, 2), 384, 0, stream>>>(xz, conv1d_w, conv1d_b,
                                                   u_b0, u_b1);
  gemm128_k<2, 0><<<dim3(4, 64, 2), 256, 0, stream>>>(u_b0, u_b1, Wcomb, 384, 512,
                                                      de0, de1, bc0, bc1,
                                                      dt_proj_b);
  scan1_k<<<dim3(12, 8, 32), 512, 0, stream>>>(de0, de1, u_b0, u_b1, bc0, bc1,
                                               A2, PH);
  scan2_k<<<dim3(12, 8, 32), 512, 0, stream>>>(de0, de1, u_b0, u_b1, bc0, bc1,
                                               xz, A2, D_param, PH, Sb0, Sb1);
  gemm128_k<3, 1><<<dim3(3, 64), 256, 0, stream>>>(Sb0, Sb1, W_out, 384, 384,
                                                   Gb, Gb, nullptr, nullptr,
                                                   scale_mod);
  final_k<<<dim3(32, 6, 8), 256, 0, stream>>>(Gb, xb, nf, norm_w, x, dw_w, dw_b,
                                              res_scale, out);
}

// Round 9
// 245.390 us; speedup vs baseline: 1.1263x; 1.0735x over previous
//
#include <hip/hip_runtime.h>
#include <hip/hip_bf16.h>

// HiMambaBottleneck: B=8, C=384, H=W=32, L=1024, BL=8192, dt_rank=24, N=16.
//  - bf16 mid-pipeline; rmsnorm folded into W_in + in_proj epilogue.
//  - delta GEMM fused with x_proj B/C via combined weight Wcomb[512][384].
//  - GEMMs: 64^2 tiles, high occupancy (~6 blocks/CU), reg-prefetch dbuf.
//    (128^2 + global_load_lds was a latency trap at K=384 / small grids.)
//  - scan: 2-pass segmented 16x64, f32 LDS, prefetch-all + single barrier;
//    scan2 LDS y-stash -> coalesced ushort4 stores; combine merged (PH).

typedef __attribute__((ext_vector_type(8))) short bf16x8;
typedef __attribute__((ext_vector_type(8))) unsigned short u16x8;
typedef __attribute__((ext_vector_type(4))) float f32x4;

#define L2E 1.44269504088896340736f

static __device__ __forceinline__ unsigned short f2bf(float f) {
  unsigned int u = __builtin_bit_cast(unsigned int, f);
  u += 0x7fff + ((u >> 16) & 1);  // RNE
  return (unsigned short)(u >> 16);
}
static __device__ __forceinline__ float bf2f(unsigned short u) {
  unsigned int v = (unsigned int)u << 16;
  return __builtin_bit_cast(float, v);
}

// ---------------- prep: weights -> bf16 (padded), A2, Wcomb ---------------
__global__ __launch_bounds__(256) void prep_k(
    const float* __restrict__ in_w, const float* __restrict__ x_w,
    const float* __restrict__ dt_w, const float* __restrict__ out_w,
    const float* __restrict__ A_log, const float* __restrict__ nw,
    unsigned short* __restrict__ W_in, unsigned short* __restrict__ W_out,
    unsigned short* __restrict__ Wcomb, float* __restrict__ A2) {
  int idx = blockIdx.x * 256 + threadIdx.x;
  switch (blockIdx.y) {
    case 0: if (idx < 768 * 384) W_in[idx] = f2bf(in_w[idx] * nw[idx % 384]); break;
    case 1: if (idx < 384 * 384) W_out[idx] = f2bf(out_w[idx]); break;
    case 2: if (idx < 384 * 16) A2[idx] = -expf(A_log[idx]) * L2E; break;
    case 3: if (idx < 384 * 384) {            // Wcomb rows 0..383: dt_w . x_w
        int o = idx / 384, c = idx - o * 384;
        float s = 0.f;
        #pragma unroll
        for (int r = 0; r < 24; ++r) s += dt_w[o * 24 + r] * x_w[r * 384 + c];
        Wcomb[idx] = f2bf(s);
      } break;
    case 4: if (idx < 128 * 384) {            // Wcomb rows 384..511: B/C + pad
        int n = idx / 384, k = idx - n * 384;
        Wcomb[147456 + idx] = f2bf(n < 32 ? x_w[(24 + n) * 384 + k] : 0.f);
      } break;
  }
}

// ---------------- transpose-lite: x NCHW -> xb (CL bf16) + nf[bl] ---------
__global__ __launch_bounds__(256) void transpose_k(
    const float* __restrict__ x, unsigned short* __restrict__ xb,
    float* __restrict__ nf) {
  const int b = blockIdx.y;
  const int l0 = blockIdx.x * 32;
  const int tid = threadIdx.x;
  const int cr = tid >> 5, lw = tid & 31;
  const int cj = tid & 63, lr = tid >> 6;
  __shared__ float t64[64][33];
  __shared__ float part[8][33];
  float acc = 0.f;
  for (int cc = 0; cc < 6; ++cc) {
    #pragma unroll
    for (int k = 0; k < 8; ++k) {
      int cp = k * 8 + cr;
      int c = cc * 64 + cp;
      float v = x[(((size_t)(b * 384 + c)) << 10) + l0 + lw];
      t64[cp][lw] = v;
      acc = fmaf(v, v, acc);
    }
    __syncthreads();
    #pragma unroll
    for (int k2 = 0; k2 < 8; ++k2) {
      int ll = lr + 4 * k2;
      xb[((size_t)((b << 10) + l0 + ll)) * 384 + cc * 64 + cj] = f2bf(t64[cj][ll]);
    }
    __syncthreads();
  }
  part[cr][lw] = acc;
  __syncthreads();
  if (tid < 32) {
    float s = part[0][tid] + part[1][tid] + part[2][tid] + part[3][tid] +
              part[4][tid] + part[5][tid] + part[6][tid] + part[7][tid];
    nf[(b << 10) + l0 + tid] = rsqrtf(s * (1.f / 384.f) + 1e-6f);
  }
}

// ---------------- 64^2 MFMA GEMM, reg-prefetch double-buffer --------------
// EPI 0: in_proj (bf16 out x nf[m]); EPI 2: delta+bc (n<384 softplus->de,
// 384<=n<416 -> bc f32; dir via z); EPI 3: out_proj (SUMIN S0+S1, bf16 x
// scale). grid (N-tiles, M-tiles, dir).
template <int EPI, int SUMIN>
__global__ __launch_bounds__(256) void gemm64_k(
    const unsigned short* __restrict__ A0u, const unsigned short* __restrict__ A1u,
    const unsigned short* __restrict__ Bw, int K, int N,
    unsigned short* __restrict__ ob0, unsigned short* __restrict__ ob1,
    float* __restrict__ of0, float* __restrict__ of1,
    const float* __restrict__ aux) {
  const unsigned short* Au = blockIdx.z ? A1u : A0u;
  unsigned short* ob = blockIdx.z ? ob1 : ob0;
  float* of = blockIdx.z ? of1 : of0;
  __shared__ unsigned short As[64][40];
  __shared__ unsigned short Bs[64][40];
  const int n0 = blockIdx.x * 64, m0 = blockIdx.y * 64;
  const int tid = threadIdx.x;
  const int lane = tid & 63, wave = tid >> 6;
  const int wm = wave >> 1, wn = wave & 1;
  const int lrow = tid >> 2, lseg = (tid & 3) * 8;
  const int fr = lane & 15, ks = (lane >> 4) * 8;
  const unsigned short* pA = Au + (size_t)(m0 + lrow) * K + lseg;
  const unsigned short* pA1 = A1u + (size_t)(m0 + lrow) * K + lseg;
  const unsigned short* pB = Bw + (size_t)(n0 + lrow) * K + lseg;
  u16x8 rva, rvb, rbb;
  auto issue = [&](int k0) {            // loads only (stay in flight)
    rva = *(const u16x8*)(pA + k0);
    if (SUMIN) rvb = *(const u16x8*)(pA1 + k0);
    rbb = *(const u16x8*)(pB + k0);
  };
  auto commit = [&]() {                 // convert + LDS write
    u16x8 s = rva;
    if (SUMIN) {
      #pragma unroll
      for (int j = 0; j < 8; ++j) s[j] = f2bf(bf2f(rva[j]) + bf2f(rvb[j]));
    }
    *(u16x8*)&As[lrow][lseg] = s;
    *(u16x8*)&Bs[lrow][lseg] = rbb;
  };
  issue(0);
  f32x4 acc[2][2] = {};
  for (int k0 = 0; k0 < K; k0 += 32) {
    __syncthreads();                    // prior fragment reads done
    commit();
    __syncthreads();                    // LDS tile ready
    if (k0 + 32 < K) issue(k0 + 32);    // next loads under the MFMAs
    bf16x8 a0 = *(const bf16x8*)&As[wm * 32 + fr][ks];
    bf16x8 a1 = *(const bf16x8*)&As[wm * 32 + 16 + fr][ks];
    bf16x8 b0 = *(const bf16x8*)&Bs[wn * 32 + fr][ks];
    bf16x8 b1 = *(const bf16x8*)&Bs[wn * 32 + 16 + fr][ks];
    acc[0][0] = __builtin_amdgcn_mfma_f32_16x16x32_bf16(a0, b0, acc[0][0], 0, 0, 0);
    acc[0][1] = __builtin_amdgcn_mfma_f32_16x16x32_bf16(a0, b1, acc[0][1], 0, 0, 0);
    acc[1][0] = __builtin_amdgcn_mfma_f32_16x16x32_bf16(a1, b0, acc[1][0], 0, 0, 0);
    acc[1][1] = __builtin_amdgcn_mfma_f32_16x16x32_bf16(a1, b1, acc[1][1], 0, 0, 0);
  }
  #pragma unroll
  for (int mi = 0; mi < 2; ++mi)
    #pragma unroll
    for (int ni = 0; ni < 2; ++ni)
      #pragma unroll
      for (int j = 0; j < 4; ++j) {
        int m = m0 + wm * 32 + mi * 16 + (lane >> 4) * 4 + j;
        int n = n0 + wn * 32 + ni * 16 + (lane & 15);
        float v = acc[mi][ni][j];
        if (EPI == 0) {
          ob0[(size_t)m * N + n] = f2bf(v * aux[m]);        // x nf[m] -> xz
        } else if (EPI == 2) {
          if (n < 384) {
            float t = v + aux[n];
            float sp = (t > 20.f) ? t : log1pf(expf(t));
            ob[(size_t)m * 384 + n] = f2bf(sp);             // delta bf16
          } else if (n < 416) {
            of[(size_t)m * 32 + (n - 384)] = v;             // B/C f32
          }
        } else {
          ob0[(size_t)m * N + n] = f2bf(v * aux[0]);        // G bf16
        }
      }
}

// ---------------- causal depthwise conv1d + silu (both directions) --------
__global__ __launch_bounds__(384) void conv_silu_k(
    const unsigned short* __restrict__ xz, const float* __restrict__ cw,
    const float* __restrict__ cb,
    unsigned short* __restrict__ ub0, unsigned short* __restrict__ ub1) {
  const int st = blockIdx.x, b = blockIdx.y, dir = blockIdx.z;
  const int c = threadIdx.x;
  const int s0 = st * 8;
  const float w0 = cw[c * 4 + 0], w1 = cw[c * 4 + 1];
  const float w2 = cw[c * 4 + 2], w3 = cw[c * 4 + 3];
  const float bb = cb[c];
  unsigned short* ub = dir ? ub1 : ub0;
  float xv[11];
  #pragma unroll
  for (int k = 0; k < 11; ++k) {
    int j = s0 - 3 + k;
    float v = 0.f;
    if (j >= 0) {
      int t = dir ? (1023 - j) : j;
      v = bf2f(xz[(size_t)((b << 10) + t) * 768 + c]);
    }
    xv[k] = v;
  }
  #pragma unroll
  for (int s = 0; s < 8; ++s) {
    float a = bb + xv[s] * w0 + xv[s + 1] * w1 + xv[s + 2] * w2 + xv[s + 3] * w3;
    float uv = a * __builtin_amdgcn_rcpf(1.f + __builtin_amdgcn_exp2f(-a * L2E));
    ub[(size_t)((b << 10) + s0 + s) * 384 + c] = f2bf(uv);
  }
}

// ---------------- scan pass 1: per-segment (P, h) -> PH interleaved -------
// grid (12 ct, 8 b, 32 = dir*16+seg); 512 thr; prefetch-all, 1 barrier.
__global__ __launch_bounds__(512) void scan1_k(
    const unsigned short* __restrict__ de0, const unsigned short* __restrict__ de1,
    const unsigned short* __restrict__ ub0, const unsigned short* __restrict__ ub1,
    const float* __restrict__ bc0, const float* __restrict__ bc1,
    const float* __restrict__ A2, float* __restrict__ PH) {
  const int ct = blockIdx.x, b = blockIdx.y;
  const int dir = blockIdx.z >> 4, seg = blockIdx.z & 15;
  const unsigned short* del = dir ? de1 : de0;
  const unsigned short* uu  = dir ? ub1 : ub0;
  const float* bc  = dir ? bc1 : bc0;
  const int tid = threadIdx.x;
  const int lane = tid & 63, wave = tid >> 6;
  const int n = lane & 15, cg = lane >> 4;
  const int cl = wave * 4 + cg;
  const int c = ct * 32 + cl;
  const float a2 = A2[c * 16 + n];
  const size_t base = ((size_t)b << 10) + seg * 64;
  __shared__ __attribute__((aligned(16))) float sd[32][68];
  __shared__ __attribute__((aligned(16))) float su[32][68];
  __shared__ __attribute__((aligned(16))) float sB[16][68];
  const int li = tid >> 5, lj = tid & 31;
  const int li3 = tid >> 4, lj3 = tid & 15;
  unsigned short rd[4], ru[4];
  float rb[2];
  #pragma unroll
  for (int k = 0; k < 4; ++k) {
    size_t rowi = base + k * 16 + li;
    rd[k] = del[rowi * 384 + ct * 32 + lj];
    ru[k] = uu [rowi * 384 + ct * 32 + lj];
  }
  #pragma unroll
  for (int k = 0; k < 2; ++k)
    rb[k] = bc[(base + k * 32 + li3) * 32 + lj3];
  #pragma unroll
  for (int k = 0; k < 4; ++k) {
    float dd = bf2f(rd[k]);
    sd[lj][k * 16 + li] = dd;
    su[lj][k * 16 + li] = dd * bf2f(ru[k]);   // premultiplied d*u
  }
  #pragma unroll
  for (int k = 0; k < 2; ++k) sB[lj3][k * 32 + li3] = rb[k];
  __syncthreads();
  float h = 0.f, P = 1.f;
  for (int ch = 0; ch < 4; ++ch) {
    f32x4 dv[4], duv[4], bmv[4];
    #pragma unroll
    for (int r = 0; r < 4; ++r) {
      dv[r]  = *(const f32x4*)&sd[cl][ch * 16 + r * 4];
      duv[r] = *(const f32x4*)&su[cl][ch * 16 + r * 4];
      bmv[r] = *(const f32x4*)&sB[n][ch * 16 + r * 4];
    }
    #pragma unroll
    for (int i = 0; i < 16; ++i) {
      float dA = __builtin_amdgcn_exp2f(dv[i >> 2][i & 3] * a2);
      h = fmaf(dA, h, duv[i >> 2][i & 3] * bmv[i >> 2][i & 3]);
      P *= dA;
    }
  }
  size_t o = (size_t)((dir * 8 + b) * 16 + seg) * 6144 + c * 16 + n;
  *(float2*)&PH[o * 2] = make_float2(P, h);
}

// ---------------- scan pass 2: seeded full scan + gate (combine merged) ---
__global__ __launch_bounds__(512) void scan2_k(
    const unsigned short* __restrict__ de0, const unsigned short* __restrict__ de1,
    const unsigned short* __restrict__ ub0, const unsigned short* __restrict__ ub1,
    const float* __restrict__ bc0, const float* __restrict__ bc1,
    const unsigned short* __restrict__ xz, const float* __restrict__ A2,
    const float* __restrict__ Dp, const float* __restrict__ PH,
    unsigned short* __restrict__ Sb0, unsigned short* __restrict__ Sb1) {
  const int ct = blockIdx.x, b = blockIdx.y;
  const int dir = blockIdx.z >> 4, seg = blockIdx.z & 15;
  const unsigned short* del = dir ? de1 : de0;
  const unsigned short* uu  = dir ? ub1 : ub0;
  const float* bc  = dir ? bc1 : bc0;
  unsigned short* S = dir ? Sb1 : Sb0;
  const int tid = threadIdx.x;
  const int lane = tid & 63, wave = tid >> 6;
  const int n = lane & 15, cg = lane >> 4;
  const int cl = wave * 4 + cg;
  const int c = ct * 32 + cl;
  const float a2 = A2[c * 16 + n];
  const float dpc = Dp[c];
  const size_t bb_ = (size_t)b << 10;
  const int segoff = seg * 64;
  __shared__ __attribute__((aligned(16))) float sd[32][68];
  __shared__ __attribute__((aligned(16))) float su[32][68];
  __shared__ __attribute__((aligned(16))) float sz[32][68];
  __shared__ __attribute__((aligned(16))) float sbc[32][68];
  __shared__ __attribute__((aligned(16))) unsigned short sy[64 * 36];
  const int li = tid >> 5, lj = tid & 31;
  unsigned short rd[4], ru[4], rz[4];
  float rb[4];
  #pragma unroll
  for (int k = 0; k < 4; ++k) {
    size_t rowi = bb_ + segoff + k * 16 + li;
    rd[k] = del[rowi * 384 + ct * 32 + lj];
    ru[k] = uu [rowi * 384 + ct * 32 + lj];
    int tz = dir ? (1023 - (segoff + k * 16 + li)) : (segoff + k * 16 + li);
    rz[k] = xz[(bb_ + tz) * 768 + 384 + ct * 32 + lj];
    rb[k] = bc[rowi * 32 + lj];
  }
  // prefix combine seed (independent loads, L2-resident)
  float h = 0.f;
  {
    size_t rb2 = (((size_t)(dir * 8 + b) * 16) * 6144 + c * 16 + n) * 2;
    #pragma unroll
    for (int s = 0; s < 15; ++s) {
      float2 ph = *(const float2*)&PH[rb2 + (size_t)s * 12288];
      h = (s < seg) ? fmaf(ph.x, h, ph.y) : h;
    }
  }
  #pragma unroll
  for (int k = 0; k < 4; ++k) {
    sd[lj][k * 16 + li] = bf2f(rd[k]);
    su[lj][k * 16 + li] = bf2f(ru[k]);
    sz[lj][k * 16 + li] = bf2f(rz[k]);
    sbc[lj][k * 16 + li] = rb[k];
  }
  __syncthreads();
  for (int ch = 0; ch < 4; ++ch) {
    f32x4 dv[4], uv4[4], bmv[4], cmv[4];
    #pragma unroll
    for (int r = 0; r < 4; ++r) {
      dv[r]  = *(const f32x4*)&sd[cl][ch * 16 + r * 4];
      uv4[r] = *(const f32x4*)&su[cl][ch * 16 + r * 4];
      bmv[r] = *(const f32x4*)&sbc[n][ch * 16 + r * 4];
      cmv[r] = *(const f32x4*)&sbc[16 + n][ch * 16 + r * 4];
    }
    float p[16];
    #pragma unroll
    for (int i = 0; i < 16; ++i) {
      float dd = dv[i >> 2][i & 3];
      float dA = __builtin_amdgcn_exp2f(dd * a2);
      h = fmaf(dA, h, dd * uv4[i >> 2][i & 3] * bmv[i >> 2][i & 3]);
      p[i] = h * cmv[i >> 2][i & 3];
    }
    // distributed butterfly: y[t] = sum_n p_n[t]; lane n ends with t=n.
    float q8[8];
    #pragma unroll
    for (int j = 0; j < 8; ++j) {
      float send = (n & 8) ? p[j] : p[j + 8];
      float recv = __shfl_xor(send, 8);
      float keep = (n & 8) ? p[j + 8] : p[j];
      q8[j] = keep + recv;
    }
    float q4[4];
    #pragma unroll
    for (int j = 0; j < 4; ++j) {
      float send = (n & 4) ? q8[j] : q8[j + 4];
      float recv = __shfl_xor(send, 4);
      float keep = (n & 4) ? q8[j + 4] : q8[j];
      q4[j] = keep + recv;
    }
    float q2[2];
    #pragma unroll
    for (int j = 0; j < 2; ++j) {
      float send = (n & 2) ? q4[j] : q4[j + 2];
      float recv = __shfl_xor(send, 2);
      float keep = (n & 2) ? q4[j + 2] : q4[j];
      q2[j] = keep + recv;
    }
    float send = (n & 1) ? q2[0] : q2[1];
    float recv = __shfl_xor(send, 1);
    float keep = (n & 1) ? q2[1] : q2[0];
    float ysum = keep + recv;
    // gate: lane n owns timestep segoff + ch*16 + n of channel c
    float uvn = su[cl][ch * 16 + n];
    float zz  = sz[cl][ch * 16 + n];
    float sig = __builtin_amdgcn_rcpf(1.f + __builtin_amdgcn_exp2f(-zz * L2E));
    float y = (ysum + uvn * dpc) * (zz * sig);
    sy[(ch * 16 + n) * 36 + cl] = f2bf(y);
  }
  __syncthreads();
  {
    const int t = tid >> 3, cq = (tid & 7) * 4;
    int tg = segoff + t;
    int trow = dir ? (1023 - tg) : tg;
    *(ushort4*)&S[(bb_ + trow) * 384 + ct * 32 + cq] =
        *(const ushort4*)&sy[t * 36 + cq];
  }
}

// ---------------- final: dwconv3x3 gate + transpose + residual ------------
__global__ __launch_bounds__(256) void final_k(
    const unsigned short* __restrict__ Gb, const unsigned short* __restrict__ xb,
    const float* __restrict__ nf, const float* __restrict__ nw,
    const float* __restrict__ x, const float* __restrict__ dww,
    const float* __restrict__ dwb, const float* __restrict__ rs,
    float* __restrict__ out) {
  __shared__ float tile[64][33];
  __shared__ float wq[9][64];
  __shared__ float bbs[64], nws[64];
  const int l0 = blockIdx.x * 32, c0 = blockIdx.y * 64, b = blockIdx.z;
  const int tid = threadIdx.x;
  for (int i = tid; i < 576; i += 256) {
    int c = i / 9, q = i - c * 9;
    wq[q][c] = dww[(size_t)(c0 + c) * 9 + q] * nw[c0 + c];
  }
  if (tid < 64) { bbs[tid] = dwb[c0 + tid]; nws[tid] = nw[c0 + tid]; }
  __syncthreads();
  {
    const int oct = tid & 7, li = tid >> 3;
    const int l = l0 + li;
    const int hh = l >> 5, ww = l & 31;
    float acc[8];
    {
      f32x4 ba = *(const f32x4*)&bbs[oct * 8];
      f32x4 bb2 = *(const f32x4*)&bbs[oct * 8 + 4];
      #pragma unroll
      for (int j = 0; j < 4; ++j) { acc[j] = ba[j]; acc[j + 4] = bb2[j]; }
    }
    #pragma unroll
    for (int di = -1; di <= 1; ++di) {
      int h2 = hh + di;
      if (h2 < 0 || h2 > 31) continue;
      #pragma unroll
      for (int dj = -1; dj <= 1; ++dj) {
        int w2 = ww + dj;
        if (w2 < 0 || w2 > 31) continue;
        int lp = h2 * 32 + w2;
        float nfl = nf[(b << 10) + lp];
        u16x8 v = *(const u16x8*)&xb[(size_t)((b << 10) + lp) * 384 + c0 + oct * 8];
        int q = (di + 1) * 3 + (dj + 1);
        f32x4 wa = *(const f32x4*)&wq[q][oct * 8];
        f32x4 wb = *(const f32x4*)&wq[q][oct * 8 + 4];
        #pragma unroll
        for (int j = 0; j < 4; ++j) {
          acc[j]     = fmaf(bf2f(v[j]) * nfl, wa[j], acc[j]);
          acc[j + 4] = fmaf(bf2f(v[j + 4]) * nfl, wb[j], acc[j + 4]);
        }
      }
    }
    size_t ri = (size_t)((b << 10) + l) * 384 + c0 + oct * 8;
    float nfl0 = nf[(b << 10) + l];
    u16x8 xc = *(const u16x8*)&xb[ri];
    u16x8 gv = *(const u16x8*)&Gb[ri];
    #pragma unroll
    for (int j = 0; j < 8; ++j) {
      float xv = bf2f(xc[j]) * nfl0 * nws[oct * 8 + j];
      float sig = __builtin_amdgcn_rcpf(1.f + __builtin_amdgcn_exp2f(-acc[j] * L2E));
      tile[oct * 8 + j][li] = bf2f(gv[j]) + xv * sig;
    }
  }
  __syncthreads();
  {
    const int lw = tid & 31, cr = tid >> 5;
    const float rsv = rs[0];
    for (int p = 0; p < 8; ++p) {
      int c = c0 + p * 8 + cr;
      size_t o = ((size_t)(b * 384 + c) << 10) + l0 + lw;
      out[o] = x[o] + rsv * tile[p * 8 + cr][lw];
    }
  }
}

// ---------------- host ----------------------------------------------------
extern "C" void kernel_launch(void* const* d_in, const int* in_sizes, int n_in,
                              void* d_out, int out_size, void* d_ws, size_t ws_size,
                              hipStream_t stream) {
  const float* x         = (const float*)d_in[0];
  const float* norm_w    = (const float*)d_in[1];
  const float* in_proj_w = (const float*)d_in[2];
  const float* conv1d_w  = (const float*)d_in[3];
  const float* conv1d_b  = (const float*)d_in[4];
  const float* x_proj_w  = (const float*)d_in[5];
  const float* dt_proj_w = (const float*)d_in[6];
  const float* dt_proj_b = (const float*)d_in[7];
  const float* A_log     = (const float*)d_in[8];
  const float* D_param   = (const float*)d_in[9];
  const float* out_proj_w= (const float*)d_in[10];
  const float* scale_mod = (const float*)d_in[11];
  const float* dw_w      = (const float*)d_in[12];
  const float* dw_b      = (const float*)d_in[13];
  const float* res_scale = (const float*)d_in[14];
  float* out = (float*)d_out;

  char* base = (char*)d_ws;
  size_t off = 0;
  auto alloc = [&](size_t bytes) {
    off = (off + 255) & ~(size_t)255;
    void* p = base + off;
    off += bytes;
    return p;
  };
  const size_t B_BLC = (size_t)8192 * 384 * 2;

  unsigned short* xb   = (unsigned short*)alloc(B_BLC);
  float*          nf   = (float*)alloc((size_t)8192 * 4);
  unsigned short* xz   = (unsigned short*)alloc((size_t)8192 * 768 * 2);
  unsigned short* u_b0 = (unsigned short*)alloc(B_BLC);
  unsigned short* u_b1 = (unsigned short*)alloc(B_BLC);
  float*          bc0  = (float*)alloc((size_t)8192 * 32 * 4);
  float*          bc1  = (float*)alloc((size_t)8192 * 32 * 4);
  unsigned short* de0  = (unsigned short*)alloc(B_BLC);
  unsigned short* de1  = (unsigned short*)alloc(B_BLC);
  unsigned short* Sb0  = (unsigned short*)alloc(B_BLC);
  unsigned short* Sb1  = (unsigned short*)alloc(B_BLC);
  float*          PH   = (float*)alloc((size_t)1572864 * 2 * 4);
  unsigned short* W_in = (unsigned short*)alloc((size_t)768 * 384 * 2);
  unsigned short* W_out= (unsigned short*)alloc((size_t)384 * 384 * 2);
  unsigned short* Wcomb= (unsigned short*)alloc((size_t)512 * 384 * 2);
  float*          A2   = (float*)alloc((size_t)384 * 16 * 4);
  unsigned short* Gb   = (unsigned short*)alloc(B_BLC);

  prep_k<<<dim3(1152, 5), 256, 0, stream>>>(in_proj_w, x_proj_w, dt_proj_w,
                                            out_proj_w, A_log, norm_w,
                                            W_in, W_out, Wcomb, A2);
  transpose_k<<<dim3(32, 8), 256, 0, stream>>>(x, xb, nf);
  gemm64_k<0, 0><<<dim3(12, 128), 256, 0, stream>>>(xb, xb, W_in, 384, 768,
                                                    xz, xz, nullptr, nullptr, nf);
  conv_silu_k<<<dim3(128, 8, 2), 384, 0, stream>>>(xz, conv1d_w, conv1d_b,
                                                   u_b0, u_b1);
  gemm64_k<2, 0><<<dim3(7, 128, 2), 256, 0, stream>>>(u_b0, u_b1, Wcomb, 384, 512,
                                                      de0, de1, bc0, bc1,
                                                      dt_proj_b);
  scan1_k<<<dim3(12, 8, 32), 512, 0, stream>>>(de0, de1, u_b0, u_b1, bc0, bc1,
                                               A2, PH);
  scan2_k<<<dim3(12, 8, 32), 512, 0, stream>>>(de0, de1, u_b0, u_b1, bc0, bc1,
                                               xz, A2, D_param, PH, Sb0, Sb1);
  gemm64_k<3, 1><<<dim3(6, 128), 256, 0, stream>>>(Sb0, Sb1, W_out, 384, 384,
                                                   Gb, Gb, nullptr, nullptr,
                                                   scale_mod);
  final_k<<<dim3(32, 6, 8), 256, 0, stream>>>(Gb, xb, nf, norm_w, x, dw_w, dw_b,
                                              res_scale, out);
}

// Round 10
// 243.858 us; speedup vs baseline: 1.1334x; 1.0063x over previous
//
#include <hip/hip_runtime.h>
#include <hip/hip_bf16.h>

// HiMambaBottleneck: B=8, C=384, H=W=32, L=1024, BL=8192, dt_rank=24, N=16.
//  - bf16 mid-pipeline; rmsnorm folded into W_in + in_proj epilogue.
//  - delta GEMM fused with x_proj B/C via combined weight Wcomb[512][384].
//  - GEMMs: 64^2 tiles, high occupancy, reg-prefetch dbuf (proven R9).
//  - scan: 2-pass segmented 16x64, f32 LDS, prefetch-all + single barrier;
//    scan2: premultiplied d*u staging (gate u via rcp), LDS y-stash stores.
//  - prep merged into transpose kernel (8 launches total).

typedef __attribute__((ext_vector_type(8))) short bf16x8;
typedef __attribute__((ext_vector_type(8))) unsigned short u16x8;
typedef __attribute__((ext_vector_type(4))) float f32x4;

#define L2E 1.44269504088896340736f

static __device__ __forceinline__ unsigned short f2bf(float f) {
  unsigned int u = __builtin_bit_cast(unsigned int, f);
  u += 0x7fff + ((u >> 16) & 1);  // RNE
  return (unsigned short)(u >> 16);
}
static __device__ __forceinline__ float bf2f(unsigned short u) {
  unsigned int v = (unsigned int)u << 16;
  return __builtin_bit_cast(float, v);
}

// ---------------- prep (weights->bf16, A2, Wcomb) + transpose/nf ----------
// grid (576, 6): y=0..4 prep slabs, y=5 transpose (x<256: 32 l-tiles x 8 b).
__global__ __launch_bounds__(256) void prep_tr_k(
    const float* __restrict__ in_w, const float* __restrict__ x_w,
    const float* __restrict__ dt_w, const float* __restrict__ out_w,
    const float* __restrict__ A_log, const float* __restrict__ nw,
    const float* __restrict__ x,
    unsigned short* __restrict__ W_in, unsigned short* __restrict__ W_out,
    unsigned short* __restrict__ Wcomb, float* __restrict__ A2,
    unsigned short* __restrict__ xb, float* __restrict__ nf) {
  const int tid = threadIdx.x;
  if (blockIdx.y < 5) {
    int idx = blockIdx.x * 256 + tid;
    switch (blockIdx.y) {
      case 0: {                               // W_in, 2 elems/thread
        int i2 = idx * 2;
        if (i2 < 768 * 384) {
          W_in[i2]     = f2bf(in_w[i2] * nw[i2 % 384]);
          W_in[i2 + 1] = f2bf(in_w[i2 + 1] * nw[(i2 + 1) % 384]);
        }
      } break;
      case 1: if (idx < 384 * 384) W_out[idx] = f2bf(out_w[idx]); break;
      case 2: if (idx < 384 * 16) A2[idx] = -expf(A_log[idx]) * L2E; break;
      case 3: if (idx < 384 * 384) {          // Wcomb rows 0..383: dt_w . x_w
          int o = idx / 384, c = idx - o * 384;
          float s = 0.f;
          #pragma unroll
          for (int r = 0; r < 24; ++r) s += dt_w[o * 24 + r] * x_w[r * 384 + c];
          Wcomb[idx] = f2bf(s);
        } break;
      case 4: if (idx < 128 * 384) {          // Wcomb rows 384..511: B/C + pad
          int n = idx / 384, k = idx - n * 384;
          Wcomb[147456 + idx] = f2bf(n < 32 ? x_w[(24 + n) * 384 + k] : 0.f);
        } break;
    }
    return;
  }
  // ---- transpose part ----
  const int bx = blockIdx.x;
  if (bx >= 256) return;
  const int b = bx >> 5;
  const int l0 = (bx & 31) * 32;
  const int cr = tid >> 5, lw = tid & 31;
  const int cj = tid & 63, lr = tid >> 6;
  __shared__ float t64[64][33];
  __shared__ float part[8][33];
  float acc = 0.f;
  for (int cc = 0; cc < 6; ++cc) {
    #pragma unroll
    for (int k = 0; k < 8; ++k) {
      int cp = k * 8 + cr;
      int c = cc * 64 + cp;
      float v = x[(((size_t)(b * 384 + c)) << 10) + l0 + lw];
      t64[cp][lw] = v;
      acc = fmaf(v, v, acc);
    }
    __syncthreads();
    #pragma unroll
    for (int k2 = 0; k2 < 8; ++k2) {
      int ll = lr + 4 * k2;
      xb[((size_t)((b << 10) + l0 + ll)) * 384 + cc * 64 + cj] = f2bf(t64[cj][ll]);
    }
    __syncthreads();
  }
  part[cr][lw] = acc;
  __syncthreads();
  if (tid < 32) {
    float s = part[0][tid] + part[1][tid] + part[2][tid] + part[3][tid] +
              part[4][tid] + part[5][tid] + part[6][tid] + part[7][tid];
    nf[(b << 10) + l0 + tid] = rsqrtf(s * (1.f / 384.f) + 1e-6f);
  }
}

// ---------------- 64^2 MFMA GEMM, reg-prefetch double-buffer --------------
// EPI 0: in_proj (bf16 out x nf[m]); EPI 2: delta+bc (n<384 softplus->de,
// 384<=n<416 -> bc f32; dir via z); EPI 3: out_proj (SUMIN S0+S1, bf16 x
// scale). grid (N-tiles, M-tiles, dir).
template <int EPI, int SUMIN>
__global__ __launch_bounds__(256) void gemm64_k(
    const unsigned short* __restrict__ A0u, const unsigned short* __restrict__ A1u,
    const unsigned short* __restrict__ Bw, int K, int N,
    unsigned short* __restrict__ ob0, unsigned short* __restrict__ ob1,
    float* __restrict__ of0, float* __restrict__ of1,
    const float* __restrict__ aux) {
  const unsigned short* Au = blockIdx.z ? A1u : A0u;
  unsigned short* ob = blockIdx.z ? ob1 : ob0;
  float* of = blockIdx.z ? of1 : of0;
  __shared__ unsigned short As[64][40];
  __shared__ unsigned short Bs[64][40];
  const int n0 = blockIdx.x * 64, m0 = blockIdx.y * 64;
  const int tid = threadIdx.x;
  const int lane = tid & 63, wave = tid >> 6;
  const int wm = wave >> 1, wn = wave & 1;
  const int lrow = tid >> 2, lseg = (tid & 3) * 8;
  const int fr = lane & 15, ks = (lane >> 4) * 8;
  const unsigned short* pA = Au + (size_t)(m0 + lrow) * K + lseg;
  const unsigned short* pA1 = A1u + (size_t)(m0 + lrow) * K + lseg;
  const unsigned short* pB = Bw + (size_t)(n0 + lrow) * K + lseg;
  u16x8 rva, rvb, rbb;
  auto issue = [&](int k0) {            // loads only (stay in flight)
    rva = *(const u16x8*)(pA + k0);
    if (SUMIN) rvb = *(const u16x8*)(pA1 + k0);
    rbb = *(const u16x8*)(pB + k0);
  };
  auto commit = [&]() {                 // convert + LDS write
    u16x8 s = rva;
    if (SUMIN) {
      #pragma unroll
      for (int j = 0; j < 8; ++j) s[j] = f2bf(bf2f(rva[j]) + bf2f(rvb[j]));
    }
    *(u16x8*)&As[lrow][lseg] = s;
    *(u16x8*)&Bs[lrow][lseg] = rbb;
  };
  issue(0);
  f32x4 acc[2][2] = {};
  for (int k0 = 0; k0 < K; k0 += 32) {
    __syncthreads();                    // prior fragment reads done
    commit();
    __syncthreads();                    // LDS tile ready
    if (k0 + 32 < K) issue(k0 + 32);    // next loads under the MFMAs
    bf16x8 a0 = *(const bf16x8*)&As[wm * 32 + fr][ks];
    bf16x8 a1 = *(const bf16x8*)&As[wm * 32 + 16 + fr][ks];
    bf16x8 b0 = *(const bf16x8*)&Bs[wn * 32 + fr][ks];
    bf16x8 b1 = *(const bf16x8*)&Bs[wn * 32 + 16 + fr][ks];
    acc[0][0] = __builtin_amdgcn_mfma_f32_16x16x32_bf16(a0, b0, acc[0][0], 0, 0, 0);
    acc[0][1] = __builtin_amdgcn_mfma_f32_16x16x32_bf16(a0, b1, acc[0][1], 0, 0, 0);
    acc[1][0] = __builtin_amdgcn_mfma_f32_16x16x32_bf16(a1, b0, acc[1][0], 0, 0, 0);
    acc[1][1] = __builtin_amdgcn_mfma_f32_16x16x32_bf16(a1, b1, acc[1][1], 0, 0, 0);
  }
  #pragma unroll
  for (int mi = 0; mi < 2; ++mi)
    #pragma unroll
    for (int ni = 0; ni < 2; ++ni)
      #pragma unroll
      for (int j = 0; j < 4; ++j) {
        int m = m0 + wm * 32 + mi * 16 + (lane >> 4) * 4 + j;
        int n = n0 + wn * 32 + ni * 16 + (lane & 15);
        float v = acc[mi][ni][j];
        if (EPI == 0) {
          ob0[(size_t)m * N + n] = f2bf(v * aux[m]);        // x nf[m] -> xz
        } else if (EPI == 2) {
          if (n < 384) {
            float t = v + aux[n];
            float sp = (t > 20.f) ? t : log1pf(expf(t));
            ob[(size_t)m * 384 + n] = f2bf(sp);             // delta bf16
          } else if (n < 416) {
            of[(size_t)m * 32 + (n - 384)] = v;             // B/C f32
          }
        } else {
          ob0[(size_t)m * N + n] = f2bf(v * aux[0]);        // G bf16
        }
      }
}

// ---------------- causal depthwise conv1d + silu (both directions) --------
__global__ __launch_bounds__(384) void conv_silu_k(
    const unsigned short* __restrict__ xz, const float* __restrict__ cw,
    const float* __restrict__ cb,
    unsigned short* __restrict__ ub0, unsigned short* __restrict__ ub1) {
  const int st = blockIdx.x, b = blockIdx.y, dir = blockIdx.z;
  const int c = threadIdx.x;
  const int s0 = st * 8;
  const float w0 = cw[c * 4 + 0], w1 = cw[c * 4 + 1];
  const float w2 = cw[c * 4 + 2], w3 = cw[c * 4 + 3];
  const float bb = cb[c];
  unsigned short* ub = dir ? ub1 : ub0;
  float xv[11];
  #pragma unroll
  for (int k = 0; k < 11; ++k) {
    int j = s0 - 3 + k;
    float v = 0.f;
    if (j >= 0) {
      int t = dir ? (1023 - j) : j;
      v = bf2f(xz[(size_t)((b << 10) + t) * 768 + c]);
    }
    xv[k] = v;
  }
  #pragma unroll
  for (int s = 0; s < 8; ++s) {
    float a = bb + xv[s] * w0 + xv[s + 1] * w1 + xv[s + 2] * w2 + xv[s + 3] * w3;
    float uv = a * __builtin_amdgcn_rcpf(1.f + __builtin_amdgcn_exp2f(-a * L2E));
    ub[(size_t)((b << 10) + s0 + s) * 384 + c] = f2bf(uv);
  }
}

// ---------------- scan pass 1: per-segment (P, h) -> PH interleaved -------
// grid (12 ct, 8 b, 32 = dir*16+seg); 512 thr; prefetch-all, 1 barrier.
__global__ __launch_bounds__(512) void scan1_k(
    const unsigned short* __restrict__ de0, const unsigned short* __restrict__ de1,
    const unsigned short* __restrict__ ub0, const unsigned short* __restrict__ ub1,
    const float* __restrict__ bc0, const float* __restrict__ bc1,
    const float* __restrict__ A2, float* __restrict__ PH) {
  const int ct = blockIdx.x, b = blockIdx.y;
  const int dir = blockIdx.z >> 4, seg = blockIdx.z & 15;
  const unsigned short* del = dir ? de1 : de0;
  const unsigned short* uu  = dir ? ub1 : ub0;
  const float* bc  = dir ? bc1 : bc0;
  const int tid = threadIdx.x;
  const int lane = tid & 63, wave = tid >> 6;
  const int n = lane & 15, cg = lane >> 4;
  const int cl = wave * 4 + cg;
  const int c = ct * 32 + cl;
  const float a2 = A2[c * 16 + n];
  const size_t base = ((size_t)b << 10) + seg * 64;
  __shared__ __attribute__((aligned(16))) float sd[32][68];
  __shared__ __attribute__((aligned(16))) float su[32][68];
  __shared__ __attribute__((aligned(16))) float sB[16][68];
  const int li = tid >> 5, lj = tid & 31;
  const int li3 = tid >> 4, lj3 = tid & 15;
  unsigned short rd[4], ru[4];
  float rb[2];
  #pragma unroll
  for (int k = 0; k < 4; ++k) {
    size_t rowi = base + k * 16 + li;
    rd[k] = del[rowi * 384 + ct * 32 + lj];
    ru[k] = uu [rowi * 384 + ct * 32 + lj];
  }
  #pragma unroll
  for (int k = 0; k < 2; ++k)
    rb[k] = bc[(base + k * 32 + li3) * 32 + lj3];
  #pragma unroll
  for (int k = 0; k < 4; ++k) {
    float dd = bf2f(rd[k]);
    sd[lj][k * 16 + li] = dd;
    su[lj][k * 16 + li] = dd * bf2f(ru[k]);   // premultiplied d*u
  }
  #pragma unroll
  for (int k = 0; k < 2; ++k) sB[lj3][k * 32 + li3] = rb[k];
  __syncthreads();
  float h = 0.f, P = 1.f;
  for (int ch = 0; ch < 4; ++ch) {
    f32x4 dv[4], duv[4], bmv[4];
    #pragma unroll
    for (int r = 0; r < 4; ++r) {
      dv[r]  = *(const f32x4*)&sd[cl][ch * 16 + r * 4];
      duv[r] = *(const f32x4*)&su[cl][ch * 16 + r * 4];
      bmv[r] = *(const f32x4*)&sB[n][ch * 16 + r * 4];
    }
    #pragma unroll
    for (int i = 0; i < 16; ++i) {
      float dA = __builtin_amdgcn_exp2f(dv[i >> 2][i & 3] * a2);
      h = fmaf(dA, h, duv[i >> 2][i & 3] * bmv[i >> 2][i & 3]);
      P *= dA;
    }
  }
  size_t o = (size_t)((dir * 8 + b) * 16 + seg) * 6144 + c * 16 + n;
  *(float2*)&PH[o * 2] = make_float2(P, h);
}

// ---------------- scan pass 2: seeded full scan + gate (combine merged) ---
__global__ __launch_bounds__(512) void scan2_k(
    const unsigned short* __restrict__ de0, const unsigned short* __restrict__ de1,
    const unsigned short* __restrict__ ub0, const unsigned short* __restrict__ ub1,
    const float* __restrict__ bc0, const float* __restrict__ bc1,
    const unsigned short* __restrict__ xz, const float* __restrict__ A2,
    const float* __restrict__ Dp, const float* __restrict__ PH,
    unsigned short* __restrict__ Sb0, unsigned short* __restrict__ Sb1) {
  const int ct = blockIdx.x, b = blockIdx.y;
  const int dir = blockIdx.z >> 4, seg = blockIdx.z & 15;
  const unsigned short* del = dir ? de1 : de0;
  const unsigned short* uu  = dir ? ub1 : ub0;
  const float* bc  = dir ? bc1 : bc0;
  unsigned short* S = dir ? Sb1 : Sb0;
  const int tid = threadIdx.x;
  const int lane = tid & 63, wave = tid >> 6;
  const int n = lane & 15, cg = lane >> 4;
  const int cl = wave * 4 + cg;
  const int c = ct * 32 + cl;
  const float a2 = A2[c * 16 + n];
  const float dpc = Dp[c];
  const size_t bb_ = (size_t)b << 10;
  const int segoff = seg * 64;
  __shared__ __attribute__((aligned(16))) float sd[32][68];
  __shared__ __attribute__((aligned(16))) float sdu[32][68];
  __shared__ __attribute__((aligned(16))) float sz[32][68];
  __shared__ __attribute__((aligned(16))) float sbc[32][68];
  __shared__ __attribute__((aligned(16))) unsigned short sy[64 * 36];
  const int li = tid >> 5, lj = tid & 31;
  unsigned short rd[4], ru[4], rz[4];
  float rb[4];
  #pragma unroll
  for (int k = 0; k < 4; ++k) {
    size_t rowi = bb_ + segoff + k * 16 + li;
    rd[k] = del[rowi * 384 + ct * 32 + lj];
    ru[k] = uu [rowi * 384 + ct * 32 + lj];
    int tz = dir ? (1023 - (segoff + k * 16 + li)) : (segoff + k * 16 + li);
    rz[k] = xz[(bb_ + tz) * 768 + 384 + ct * 32 + lj];
    rb[k] = bc[rowi * 32 + lj];
  }
  // prefix combine seed (independent loads, L2-resident)
  float h = 0.f;
  {
    size_t rb2 = (((size_t)(dir * 8 + b) * 16) * 6144 + c * 16 + n) * 2;
    #pragma unroll
    for (int s = 0; s < 15; ++s) {
      float2 ph = *(const float2*)&PH[rb2 + (size_t)s * 12288];
      h = (s < seg) ? fmaf(ph.x, h, ph.y) : h;
    }
  }
  #pragma unroll
  for (int k = 0; k < 4; ++k) {
    float dd = bf2f(rd[k]);
    sd[lj][k * 16 + li] = dd;
    sdu[lj][k * 16 + li] = dd * bf2f(ru[k]);   // premultiplied d*u
    sz[lj][k * 16 + li] = bf2f(rz[k]);
    sbc[lj][k * 16 + li] = rb[k];
  }
  __syncthreads();
  for (int ch = 0; ch < 4; ++ch) {
    f32x4 dv[4], duv[4], bmv[4], cmv[4];
    #pragma unroll
    for (int r = 0; r < 4; ++r) {
      dv[r]  = *(const f32x4*)&sd[cl][ch * 16 + r * 4];
      duv[r] = *(const f32x4*)&sdu[cl][ch * 16 + r * 4];
      bmv[r] = *(const f32x4*)&sbc[n][ch * 16 + r * 4];
      cmv[r] = *(const f32x4*)&sbc[16 + n][ch * 16 + r * 4];
    }
    float p[16];
    #pragma unroll
    for (int i = 0; i < 16; ++i) {
      float dA = __builtin_amdgcn_exp2f(dv[i >> 2][i & 3] * a2);
      h = fmaf(dA, h, duv[i >> 2][i & 3] * bmv[i >> 2][i & 3]);
      p[i] = h * cmv[i >> 2][i & 3];
    }
    // distributed butterfly: y[t] = sum_n p_n[t]; lane n ends with t=n.
    float q8[8];
    #pragma unroll
    for (int j = 0; j < 8; ++j) {
      float send = (n & 8) ? p[j] : p[j + 8];
      float recv = __shfl_xor(send, 8);
      float keep = (n & 8) ? p[j + 8] : p[j];
      q8[j] = keep + recv;
    }
    float q4[4];
    #pragma unroll
    for (int j = 0; j < 4; ++j) {
      float send = (n & 4) ? q8[j] : q8[j + 4];
      float recv = __shfl_xor(send, 4);
      float keep = (n & 4) ? q8[j + 4] : q8[j];
      q4[j] = keep + recv;
    }
    float q2[2];
    #pragma unroll
    for (int j = 0; j < 2; ++j) {
      float send = (n & 2) ? q4[j] : q4[j + 2];
      float recv = __shfl_xor(send, 2);
      float keep = (n & 2) ? q4[j + 2] : q4[j];
      q2[j] = keep + recv;
    }
    float send = (n & 1) ? q2[0] : q2[1];
    float recv = __shfl_xor(send, 1);
    float keep = (n & 1) ? q2[1] : q2[0];
    float ysum = keep + recv;
    // gate: lane n owns timestep segoff + ch*16 + n of channel c
    float dg  = sd[cl][ch * 16 + n];
    float dug = sdu[cl][ch * 16 + n];
    float uvn = dug * __builtin_amdgcn_rcpf(dg);   // u = (d*u)/d
    float zz  = sz[cl][ch * 16 + n];
    float sig = __builtin_amdgcn_rcpf(1.f + __builtin_amdgcn_exp2f(-zz * L2E));
    float y = (ysum + uvn * dpc) * (zz * sig);
    sy[(ch * 16 + n) * 36 + cl] = f2bf(y);
  }
  __syncthreads();
  {
    const int t = tid >> 3, cq = (tid & 7) * 4;
    int tg = segoff + t;
    int trow = dir ? (1023 - tg) : tg;
    *(ushort4*)&S[(bb_ + trow) * 384 + ct * 32 + cq] =
        *(const ushort4*)&sy[t * 36 + cq];
  }
}

// ---------------- final: dwconv3x3 gate + transpose + residual ------------
__global__ __launch_bounds__(256) void final_k(
    const unsigned short* __restrict__ Gb, const unsigned short* __restrict__ xb,
    const float* __restrict__ nf, const float* __restrict__ nw,
    const float* __restrict__ x, const float* __restrict__ dww,
    const float* __restrict__ dwb, const float* __restrict__ rs,
    float* __restrict__ out) {
  __shared__ float tile[64][33];
  __shared__ float wq[9][64];
  __shared__ float bbs[64], nws[64];
  const int l0 = blockIdx.x * 32, c0 = blockIdx.y * 64, b = blockIdx.z;
  const int tid = threadIdx.x;
  for (int i = tid; i < 576; i += 256) {
    int c = i / 9, q = i - c * 9;
    wq[q][c] = dww[(size_t)(c0 + c) * 9 + q] * nw[c0 + c];
  }
  if (tid < 64) { bbs[tid] = dwb[c0 + tid]; nws[tid] = nw[c0 + tid]; }
  __syncthreads();
  {
    const int oct = tid & 7, li = tid >> 3;
    const int l = l0 + li;
    const int hh = l >> 5, ww = l & 31;
    float acc[8];
    {
      f32x4 ba = *(const f32x4*)&bbs[oct * 8];
      f32x4 bb2 = *(const f32x4*)&bbs[oct * 8 + 4];
      #pragma unroll
      for (int j = 0; j < 4; ++j) { acc[j] = ba[j]; acc[j + 4] = bb2[j]; }
    }
    #pragma unroll
    for (int di = -1; di <= 1; ++di) {
      int h2 = hh + di;
      if (h2 < 0 || h2 > 31) continue;
      #pragma unroll
      for (int dj = -1; dj <= 1; ++dj) {
        int w2 = ww + dj;
        if (w2 < 0 || w2 > 31) continue;
        int lp = h2 * 32 + w2;
        float nfl = nf[(b << 10) + lp];
        u16x8 v = *(const u16x8*)&xb[(size_t)((b << 10) + lp) * 384 + c0 + oct * 8];
        int q = (di + 1) * 3 + (dj + 1);
        f32x4 wa = *(const f32x4*)&wq[q][oct * 8];
        f32x4 wb = *(const f32x4*)&wq[q][oct * 8 + 4];
        #pragma unroll
        for (int j = 0; j < 4; ++j) {
          acc[j]     = fmaf(bf2f(v[j]) * nfl, wa[j], acc[j]);
          acc[j + 4] = fmaf(bf2f(v[j + 4]) * nfl, wb[j], acc[j + 4]);
        }
      }
    }
    size_t ri = (size_t)((b << 10) + l) * 384 + c0 + oct * 8;
    float nfl0 = nf[(b << 10) + l];
    u16x8 xc = *(const u16x8*)&xb[ri];
    u16x8 gv = *(const u16x8*)&Gb[ri];
    #pragma unroll
    for (int j = 0; j < 8; ++j) {
      float xv = bf2f(xc[j]) * nfl0 * nws[oct * 8 + j];
      float sig = __builtin_amdgcn_rcpf(1.f + __builtin_amdgcn_exp2f(-acc[j] * L2E));
      tile[oct * 8 + j][li] = bf2f(gv[j]) + xv * sig;
    }
  }
  __syncthreads();
  {
    const int lw = tid & 31, cr = tid >> 5;
    const float rsv = rs[0];
    for (int p = 0; p < 8; ++p) {
      int c = c0 + p * 8 + cr;
      size_t o = ((size_t)(b * 384 + c) << 10) + l0 + lw;
      out[o] = x[o] + rsv * tile[p * 8 + cr][lw];
    }
  }
}

// ---------------- host ----------------------------------------------------
extern "C" void kernel_launch(void* const* d_in, const int* in_sizes, int n_in,
                              void* d_out, int out_size, void* d_ws, size_t ws_size,
                              hipStream_t stream) {
  const float* x         = (const float*)d_in[0];
  const float* norm_w    = (const float*)d_in[1];
  const float* in_proj_w = (const float*)d_in[2];
  const float* conv1d_w  = (const float*)d_in[3];
  const float* conv1d_b  = (const float*)d_in[4];
  const float* x_proj_w  = (const float*)d_in[5];
  const float* dt_proj_w = (const float*)d_in[6];
  const float* dt_proj_b = (const float*)d_in[7];
  const float* A_log     = (const float*)d_in[8];
  const float* D_param   = (const float*)d_in[9];
  const float* out_proj_w= (const float*)d_in[10];
  const float* scale_mod = (const float*)d_in[11];
  const float* dw_w      = (const float*)d_in[12];
  const float* dw_b      = (const float*)d_in[13];
  const float* res_scale = (const float*)d_in[14];
  float* out = (float*)d_out;

  char* base = (char*)d_ws;
  size_t off = 0;
  auto alloc = [&](size_t bytes) {
    off = (off + 255) & ~(size_t)255;
    void* p = base + off;
    off += bytes;
    return p;
  };
  const size_t B_BLC = (size_t)8192 * 384 * 2;

  unsigned short* xb   = (unsigned short*)alloc(B_BLC);
  float*          nf   = (float*)alloc((size_t)8192 * 4);
  unsigned short* xz   = (unsigned short*)alloc((size_t)8192 * 768 * 2);
  unsigned short* u_b0 = (unsigned short*)alloc(B_BLC);
  unsigned short* u_b1 = (unsigned short*)alloc(B_BLC);
  float*          bc0  = (float*)alloc((size_t)8192 * 32 * 4);
  float*          bc1  = (float*)alloc((size_t)8192 * 32 * 4);
  unsigned short* de0  = (unsigned short*)alloc(B_BLC);
  unsigned short* de1  = (unsigned short*)alloc(B_BLC);
  unsigned short* Sb0  = (unsigned short*)alloc(B_BLC);
  unsigned short* Sb1  = (unsigned short*)alloc(B_BLC);
  float*          PH   = (float*)alloc((size_t)1572864 * 2 * 4);
  unsigned short* W_in = (unsigned short*)alloc((size_t)768 * 384 * 2);
  unsigned short* W_out= (unsigned short*)alloc((size_t)384 * 384 * 2);
  unsigned short* Wcomb= (unsigned short*)alloc((size_t)512 * 384 * 2);
  float*          A2   = (float*)alloc((size_t)384 * 16 * 4);
  unsigned short* Gb   = (unsigned short*)alloc(B_BLC);

  prep_tr_k<<<dim3(576, 6), 256, 0, stream>>>(in_proj_w, x_proj_w, dt_proj_w,
                                              out_proj_w, A_log, norm_w, x,
                                              W_in, W_out, Wcomb, A2, xb, nf);
  gemm64_k<0, 0><<<dim3(12, 128), 256, 0, stream>>>(xb, xb, W_in, 384, 768,
                                                    xz, xz, nullptr, nullptr, nf);
  conv_silu_k<<<dim3(128, 8, 2), 384, 0, stream>>>(xz, conv1d_w, conv1d_b,
                                                   u_b0, u_b1);
  gemm64_k<2, 0><<<dim3(7, 128, 2), 256, 0, stream>>>(u_b0, u_b1, Wcomb, 384, 512,
                                                      de0, de1, bc0, bc1,
                                                      dt_proj_b);
  scan1_k<<<dim3(12, 8, 32), 512, 0, stream>>>(de0, de1, u_b0, u_b1, bc0, bc1,
                                               A2, PH);
  scan2_k<<<dim3(12, 8, 32), 512, 0, stream>>>(de0, de1, u_b0, u_b1, bc0, bc1,
                                               xz, A2, D_param, PH, Sb0, Sb1);
  gemm64_k<3, 1><<<dim3(6, 128), 256, 0, stream>>>(Sb0, Sb1, W_out, 384, 384,
                                                   Gb, Gb, nullptr, nullptr,
                                                   scale_mod);
  final_k<<<dim3(32, 6, 8), 256, 0, stream>>>(Gb, xb, nf, norm_w, x, dw_w, dw_b,
                                              res_scale, out);
}